// Round 1
// baseline (531.341 us; speedup 1.0000x reference)
//
#include <hip/hip_runtime.h>
#include <hip/hip_bf16.h>
#include <stdint.h>

#define B 2
#define L 2048
#define D 1024
#define H 16
#define HD 64
#define NT (L / 64)          // 32 tiles of 64
#define INVALID_CID 0x40000000

typedef __hip_bfloat16 bf16;
typedef __attribute__((ext_vector_type(8))) short short8;
typedef __attribute__((ext_vector_type(4))) short short4v;
typedef __attribute__((ext_vector_type(4))) float floatx4;

static __device__ __forceinline__ short f2bf(float f) {
    bf16 h = __float2bfloat16(f);
    return *reinterpret_cast<short*>(&h);
}

// async global->LDS, 16B per lane; lptr must be wave-uniform (HW adds lane*16)
static __device__ __forceinline__ void async_copy16(const void* g, void* l) {
    __builtin_amdgcn_global_load_lds((__attribute__((address_space(1))) void*)g,
                                     (__attribute__((address_space(3))) void*)l,
                                     16, 0, 0);
}

// ---------------------------------------------------------------- chain info
__global__ void chain_kernel(const int* __restrict__ lens,
                             float* __restrict__ pos, int* __restrict__ cid,
                             int4* __restrict__ tinfo)
{
    __shared__ int csum[L];
    __shared__ int cids[L];
    __shared__ int part[256];
    int b = blockIdx.x;
    int t = threadIdx.x;

    int loc[8];
    int s = 0;
    #pragma unroll
    for (int j = 0; j < 8; ++j) { s += lens[b * L + t * 8 + j]; loc[j] = s; }
    part[t] = s;
    __syncthreads();
    if (t == 0) {
        int acc = 0;
        for (int i = 0; i < 256; ++i) { int v = part[i]; part[i] = acc; acc += v; }
    }
    __syncthreads();
    int base = part[t];
    #pragma unroll
    for (int j = 0; j < 8; ++j) csum[t * 8 + j] = base + loc[j];
    __syncthreads();

    int total = csum[L - 1];
    for (int p = t; p < L; p += 256) {
        int cv;
        if (p < total) {
            int lo = 0, hi = L;
            while (lo < hi) {
                int mid = (lo + hi) >> 1;
                if (csum[mid] <= p) lo = mid + 1; else hi = mid;
            }
            int prev = (lo > 0) ? csum[lo - 1] : 0;
            pos[b * L + p] = (float)(p - prev);
            cv = lo;
        } else {
            pos[b * L + p] = 0.f;
            cv = INVALID_CID;
        }
        cids[p] = cv;
        cid[b * L + p] = cv;
    }
    __syncthreads();
    if (t < NT) {
        int mn = 0x7fffffff, mx = -1, any = 0, all = 1;
        for (int j = 0; j < 64; ++j) {
            int cv = cids[t * 64 + j];
            if (cv != INVALID_CID) { any = 1; mn = min(mn, cv); mx = max(mx, cv); }
            else all = 0;
        }
        tinfo[b * NT + t] = make_int4(mn, mx, any | (all << 1), 0);
    }
}

// ---------------------------------------------------------------- cast
__global__ void cast_f32_bf16(const float* __restrict__ in, bf16* __restrict__ out, int n)
{
    int i = (blockIdx.x * 256 + threadIdx.x) * 4;
    if (i + 3 < n) {
        float4 v = *(const float4*)(in + i);
        out[i + 0] = __float2bfloat16(v.x);
        out[i + 1] = __float2bfloat16(v.y);
        out[i + 2] = __float2bfloat16(v.z);
        out[i + 3] = __float2bfloat16(v.w);
    } else {
        for (; i < n; ++i) out[i] = __float2bfloat16(in[i]);
    }
}

// ---------------------------------------------------------------- GEMM (m97-style)
// C = A * Bw^T + bias.  A:[M,K] bf16 rm, Bw:[N,K] bf16 rm. 128x128 tile, BK=32.
__global__ __launch_bounds__(256, 4) void gemm128(
    const bf16* __restrict__ A, const bf16* __restrict__ Bw,
    const float* __restrict__ bias, void* __restrict__ Cout,
    int M, int N, int K, int c_bf16)
{
    __shared__ short As[128 * 32];   // [row][32 shorts], 64B rows, lane-contiguous for DMA
    __shared__ short Bs[128 * 32];

    int tid = threadIdx.x;
    int wave = tid >> 6, lane = tid & 63;
    int i15 = lane & 15, q8 = lane >> 4;
    int wm = wave & 1, wn = wave >> 1;
    int m0 = blockIdx.y * 128, n0 = blockIdx.x * 128;

    floatx4 acc[4][4];
    #pragma unroll
    for (int mt = 0; mt < 4; ++mt)
        #pragma unroll
        for (int nt = 0; nt < 4; ++nt) acc[mt][nt] = (floatx4){0.f, 0.f, 0.f, 0.f};

    // wave stages rows [wave*32, wave*32+32) of A and B; lane i -> row base+i/4, chunk i%4
    const short* gA = (const short*)A  + (size_t)(m0 + wave * 32 + (lane >> 2)) * K + (lane & 3) * 8;
    const short* gB = (const short*)Bw + (size_t)(n0 + wave * 32 + (lane >> 2)) * K + (lane & 3) * 8;
    short* lA = As + wave * 1024;
    short* lB = Bs + wave * 1024;

    for (int kt = 0; kt < K; kt += 32) {
        __syncthreads();
        async_copy16(gA + kt,          lA);
        async_copy16(gA + 16 * K + kt, lA + 512);
        async_copy16(gB + kt,          lB);
        async_copy16(gB + 16 * K + kt, lB + 512);
        __syncthreads();

        short8 af[4], bfr[4];
        #pragma unroll
        for (int mt = 0; mt < 4; ++mt)
            af[mt] = *(const short8*)&As[(wm * 64 + mt * 16 + i15) * 32 + q8 * 8];
        #pragma unroll
        for (int nt = 0; nt < 4; ++nt)
            bfr[nt] = *(const short8*)&Bs[(wn * 64 + nt * 16 + i15) * 32 + q8 * 8];
        #pragma unroll
        for (int mt = 0; mt < 4; ++mt)
            #pragma unroll
            for (int nt = 0; nt < 4; ++nt)
                acc[mt][nt] = __builtin_amdgcn_mfma_f32_16x16x32_bf16(af[mt], bfr[nt], acc[mt][nt], 0, 0, 0);
    }

    #pragma unroll
    for (int nt = 0; nt < 4; ++nt) {
        int n = n0 + wn * 64 + nt * 16 + i15;
        float bv = bias[n];
        #pragma unroll
        for (int mt = 0; mt < 4; ++mt) {
            #pragma unroll
            for (int rg = 0; rg < 4; ++rg) {
                int m = m0 + wm * 64 + mt * 16 + q8 * 4 + rg;
                float v = acc[mt][nt][rg] + bv;
                if (c_bf16) ((bf16*)Cout)[(size_t)m * N + n] = __float2bfloat16(v);
                else        ((float*)Cout)[(size_t)m * N + n] = v;
            }
        }
    }
}

// ---------------------------------------------------------------- RoPE + scatter
// Q,K -> [B,H,L,HD]; V -> transposed [B,H,HD,L] via LDS transpose.
// Q additionally scaled by HD^-0.5 * log2(e)  (exp2-domain softmax downstream).
__global__ __launch_bounds__(256) void rope_scatter2(
    const bf16* __restrict__ qkv, const float* __restrict__ pos,
    bf16* __restrict__ Qo, bf16* __restrict__ Ko, bf16* __restrict__ Vtg)
{
    __shared__ float Vsh[64][65];   // conflict-free transpose staging
    int tid = threadIdx.x;
    int bid = blockIdx.x;
    int lt = bid & (NT - 1);
    int h  = (bid >> 5) & (H - 1);
    int b  = bid >> 9;
    int l0 = lt * 64;

    const float QSCALE = 0.18033688011111772f;  // 0.125 * log2(e)
    int hd = tid & 63, lq = tid >> 6;
    float sgn = (hd < 32) ? -1.f : 1.f;
    float invf = exp2f(-(float)(hd & 31) * (13.287712379549449f / 32.f));

    #pragma unroll
    for (int rr = 0; rr < 16; ++rr) {
        int l = l0 + lq * 16 + rr;
        size_t row = (size_t)(b * L + l) * (3 * D);
        int col  = h * HD + hd;
        int col2 = h * HD + (hd ^ 32);

        float xq  = __bfloat162float(qkv[row + col]);
        float xq2 = __bfloat162float(qkv[row + col2]);
        float xk  = __bfloat162float(qkv[row + D + col]);
        float xk2 = __bfloat162float(qkv[row + D + col2]);
        float xv  = __bfloat162float(qkv[row + 2 * D + col]);

        float p = pos[b * L + l];
        float ang = p * invf;
        float cc = cosf(ang), ss = sinf(ang);

        float qo = QSCALE * (xq * cc + sgn * xq2 * ss);
        float ko = xk * cc + sgn * xk2 * ss;

        size_t o = ((size_t)(b * H + h) * L + l) * HD + hd;
        Qo[o] = __float2bfloat16(qo);
        Ko[o] = __float2bfloat16(ko);
        Vsh[l - l0][hd] = xv;
    }
    __syncthreads();
    int lcol = tid & 63, dq = tid >> 6;
    #pragma unroll
    for (int rr = 0; rr < 16; ++rr) {
        int dd = dq * 16 + rr;
        Vtg[((size_t)(b * H + h) * HD + dd) * L + l0 + lcol] = __float2bfloat16(Vsh[lcol][dd]);
    }
}

// ---------------------------------------------------------------- MFMA flash attention v3
// k-tiles split ACROSS waves (static softmax => partial accO/lsum just add).
// K/V/Q fragments loaded global->register (no shared staging, no per-tile barriers).
// S^T = mfma(K, Q) so P-writes pack as ds_write_b64; PV computes O^T = mfma(V^T, P^T)
// with contiguous short8 P reads. Per-wave private Ps in LDS; one 3-barrier merge
// (LDS atomicAdd, Ps region reused) per block.
// branch 0 (intra): allowed = key_valid && cid_q==cid_k, writes float OutF.
// branch 1 (inter): allowed = key_valid && cid_q!=cid_k, writes bf16 OutB = o + Prev.
__global__ __launch_bounds__(256, 2) void attn3(
    const bf16* __restrict__ Q, const bf16* __restrict__ Kg, const bf16* __restrict__ Vtg,
    const int* __restrict__ cid, const int4* __restrict__ tinfo,
    float* __restrict__ OutF, bf16* __restrict__ OutB, const float* __restrict__ Prev,
    int branch)
{
    __shared__ short PsAll[4][64][72];   // per-wave P^T staging; stride 72 => conflict-free b64 w / b128 r
    __shared__ int cls_s[NT];
    __shared__ int list_s[NT];
    __shared__ int nlist_s;

    int tid = threadIdx.x;
    int wave = tid >> 6, lane = tid & 63;
    int i15 = lane & 15, q8 = lane >> 4;
    int bid = blockIdx.x;
    int qt = bid & (NT - 1);
    int h  = (bid >> 5) & (H - 1);
    int b  = bid >> 9;
    int q0 = qt * 64;
    const size_t bh  = (size_t)(b * H + h) * L;
    const size_t bhd = (size_t)(b * H + h) * HD;

    // Q fragments (B-operand of S^T): qf[qm][s] = Q[q0+qm*16+i15][s*32+q8*8 ..+7]
    short8 qf[4][2];
    {
        const short* qb = (const short*)Q + (bh + q0 + i15) * HD + q8 * 8;
        #pragma unroll
        for (int qm = 0; qm < 4; ++qm)
            #pragma unroll
            for (int s = 0; s < 2; ++s)
                qf[qm][s] = *(const short8*)(qb + qm * 16 * HD + s * 32);
    }
    int cq[4];
    #pragma unroll
    for (int qm = 0; qm < 4; ++qm) cq[qm] = cid[b * L + q0 + qm * 16 + i15];

    int4 qinf = tinfo[b * NT + qt];
    int qall = (qinf.z >> 1) & 1;

    if (tid < NT) {
        int4 ki = tinfo[b * NT + tid];
        int kany = ki.z & 1, kall = (ki.z >> 1) & 1;
        bool disjoint = (ki.x > qinf.y) || (ki.y < qinf.x);  // sentinels make !qany/!kany disjoint
        bool mono = qall && kall && (qinf.x == qinf.y) && (ki.x == ki.y) && (qinf.x == ki.x);
        int cls;
        if (branch == 0) {
            if (!kany || disjoint) cls = 0;
            else if (mono) cls = 2;
            else cls = 1;
        } else {
            if (!kany || mono) cls = 0;
            else if (kall && disjoint) cls = 2;
            else cls = 1;
        }
        cls_s[tid] = cls;
    }
    __syncthreads();
    if (tid == 0) {
        int n = 0;
        for (int t = 0; t < NT; ++t) {
            int c = cls_s[t];
            if (c) list_s[n++] = (t * 64) | ((c == 2) << 16);
        }
        nlist_s = n;
    }
    __syncthreads();
    int n = nlist_s;

    // per-lane global fragment bases
    const short* kb = (const short*)Kg  + (bh + i15) * HD + q8 * 8;
    const short* vb = (const short*)Vtg + (bhd + i15) * L + q8 * 8;
    const int*   cb = cid + b * L + q8 * 4;

    floatx4 accO[4][4];   // [dt][qm]: O^T[dt*16+q8*4+rg][qm*16+i15]
    #pragma unroll
    for (int dt = 0; dt < 4; ++dt)
        #pragma unroll
        for (int qm = 0; qm < 4; ++qm) accO[dt][qm] = (floatx4){0.f, 0.f, 0.f, 0.f};
    float lsum[4] = {0.f, 0.f, 0.f, 0.f};
    short* myPs = &PsAll[wave][0][0];

    for (int i = wave; i < n; i += 4) {
        int e = list_s[i];
        int kt = e & 0xffff, full = e >> 16;

        // K fragments (A of S^T): K[kt+t*16+i15][s*32+q8*8..+7]
        short8 kf[4][2];
        #pragma unroll
        for (int t = 0; t < 4; ++t)
            #pragma unroll
            for (int s = 0; s < 2; ++s)
                kf[t][s] = *(const short8*)(kb + (size_t)(kt + t * 16) * HD + s * 32);
        // V^T fragments (A of PV): Vt[dt*16+i15][kt+s*32+q8*8..+7]
        short8 vf[4][2];
        #pragma unroll
        for (int dt = 0; dt < 4; ++dt)
            #pragma unroll
            for (int s = 0; s < 2; ++s)
                vf[dt][s] = *(const short8*)(vb + (size_t)dt * 16 * L + kt + s * 32);
        int4 ckv[4];
        if (!full) {
            #pragma unroll
            for (int t = 0; t < 4; ++t) ckv[t] = *(const int4*)(cb + kt + t * 16);
        }

        #pragma unroll
        for (int t = 0; t < 4; ++t) {
            // S^T tile (16k x 64q): D[m=k-local][n=q]
            floatx4 accS[4];
            #pragma unroll
            for (int qm = 0; qm < 4; ++qm) accS[qm] = (floatx4){0.f, 0.f, 0.f, 0.f};
            #pragma unroll
            for (int s = 0; s < 2; ++s)
                #pragma unroll
                for (int qm = 0; qm < 4; ++qm)
                    accS[qm] = __builtin_amdgcn_mfma_f32_16x16x32_bf16(kf[t][s], qf[qm][s], accS[qm], 0, 0, 0);

            if (!full) {
                int ckr[4] = {ckv[t].x, ckv[t].y, ckv[t].z, ckv[t].w};
                #pragma unroll
                for (int qm = 0; qm < 4; ++qm)
                    #pragma unroll
                    for (int rg = 0; rg < 4; ++rg) {
                        bool kv = (ckr[rg] != INVALID_CID);
                        bool match = (cq[qm] == ckr[rg]);
                        bool ok = kv && (branch ? !match : match);
                        accS[qm][rg] = ok ? accS[qm][rg] : -1e30f;
                    }
            }

            // p = 2^s, pack 4 consecutive-k bf16 -> one b64 LDS write per (qm)
            #pragma unroll
            for (int qm = 0; qm < 4; ++qm) {
                float p0 = __builtin_amdgcn_exp2f(accS[qm][0]);
                float p1 = __builtin_amdgcn_exp2f(accS[qm][1]);
                float p2 = __builtin_amdgcn_exp2f(accS[qm][2]);
                float p3 = __builtin_amdgcn_exp2f(accS[qm][3]);
                lsum[qm] += (p0 + p1) + (p2 + p3);
                uint2 w;
                w.x = (uint)(unsigned short)f2bf(p0) | ((uint)(unsigned short)f2bf(p1) << 16);
                w.y = (uint)(unsigned short)f2bf(p2) | ((uint)(unsigned short)f2bf(p3) << 16);
                *(uint2*)&myPs[(qm * 16 + i15) * 72 + t * 16 + q8 * 4] = w;
            }
        }

        // P^T B-fragments: contiguous short8 from own Ps rows (in-wave RAW, no barrier needed)
        short8 pb[4][2];
        #pragma unroll
        for (int qm = 0; qm < 4; ++qm)
            #pragma unroll
            for (int s = 0; s < 2; ++s)
                pb[qm][s] = *(const short8*)&myPs[(qm * 16 + i15) * 72 + s * 32 + q8 * 8];

        // O^T += V^T P^T
        #pragma unroll
        for (int dt = 0; dt < 4; ++dt)
            #pragma unroll
            for (int s = 0; s < 2; ++s)
                #pragma unroll
                for (int qm = 0; qm < 4; ++qm)
                    accO[dt][qm] = __builtin_amdgcn_mfma_f32_16x16x32_bf16(vf[dt][s], pb[qm][s], accO[dt][qm], 0, 0, 0);
    }

    // ---- merge the 4 waves' partials (Ps region reused as float accumulator) ----
    __syncthreads();
    float* accOsh = (float*)&PsAll[0][0][0];     // [64 q][68] floats
    float* lsumsh = accOsh + 64 * 68;            // [64] floats
    for (int x = tid; x < 64 * 68 + 64; x += 256) accOsh[x] = 0.f;
    __syncthreads();
    #pragma unroll
    for (int qm = 0; qm < 4; ++qm) {
        atomicAdd(&lsumsh[qm * 16 + i15], lsum[qm]);
        #pragma unroll
        for (int dt = 0; dt < 4; ++dt)
            #pragma unroll
            for (int rg = 0; rg < 4; ++rg)
                atomicAdd(&accOsh[(qm * 16 + i15) * 68 + dt * 16 + q8 * 4 + rg], accO[dt][qm][rg]);
    }
    __syncthreads();

    // finale: thread -> (q = tid>>2, 16 d-cols)
    int q = tid >> 2, d0 = (tid & 3) * 16;
    float ls = lsumsh[q];
    float inv = (ls > 0.f) ? 1.f / ls : 0.f;
    size_t orow = (size_t)(b * L + q0 + q) * D + h * HD + d0;
    #pragma unroll
    for (int j = 0; j < 4; ++j) {
        float4 v;
        v.x = accOsh[q * 68 + d0 + j * 4 + 0] * inv;
        v.y = accOsh[q * 68 + d0 + j * 4 + 1] * inv;
        v.z = accOsh[q * 68 + d0 + j * 4 + 2] * inv;
        v.w = accOsh[q * 68 + d0 + j * 4 + 3] * inv;
        if (branch == 0) {
            *(float4*)&OutF[orow + j * 4] = v;
        } else {
            float4 p = *(const float4*)&Prev[orow + j * 4];
            short4v sv;
            sv[0] = f2bf(v.x + p.x);
            sv[1] = f2bf(v.y + p.y);
            sv[2] = f2bf(v.z + p.z);
            sv[3] = f2bf(v.w + p.w);
            *(short4v*)&OutB[orow + j * 4] = sv;
        }
    }
}

// ---------------------------------------------------------------- launch
extern "C" void kernel_launch(void* const* d_in, const int* in_sizes, int n_in,
                              void* d_out, int out_size, void* d_ws, size_t ws_size,
                              hipStream_t stream)
{
    const float* x    = (const float*)d_in[0];
    const int*   mlen = (const int*)  d_in[1];
    const float* Wi   = (const float*)d_in[2];
    const float* bi   = (const float*)d_in[3];
    const float* We   = (const float*)d_in[4];
    const float* be   = (const float*)d_in[5];
    const float* Wo   = (const float*)d_in[6];
    const float* bo   = (const float*)d_in[7];

    char* ws = (char*)d_ws;
    size_t off = 0;
    auto alloc = [&](size_t bytes) {
        void* p = ws + off;
        off += (bytes + 255) & ~(size_t)255;
        return p;
    };
    bf16*  x_b   = (bf16*) alloc((size_t)B * L * D * 2);
    bf16*  Wi_b  = (bf16*) alloc((size_t)3 * D * D * 2);
    bf16*  We_b  = (bf16*) alloc((size_t)3 * D * D * 2);
    bf16*  Wo_b  = (bf16*) alloc((size_t)D * D * 2);
    bf16*  qkv_b = (bf16*) alloc((size_t)B * L * 3 * D * 2);
    bf16*  q_b   = (bf16*) alloc((size_t)B * H * L * HD * 2);
    bf16*  k_b   = (bf16*) alloc((size_t)B * H * L * HD * 2);
    bf16*  vt_b  = (bf16*) alloc((size_t)B * H * HD * L * 2);
    float* att_i = (float*)alloc((size_t)B * L * D * 4);
    bf16*  sum_b = (bf16*) alloc((size_t)B * L * D * 2);
    float* pos   = (float*)alloc((size_t)B * L * 4);
    int*   cid   = (int*)  alloc((size_t)B * L * 4);
    int4*  tinfo = (int4*) alloc((size_t)B * NT * 16);
    (void)ws_size; (void)n_in; (void)in_sizes; (void)out_size;

    chain_kernel<<<B, 256, 0, stream>>>(mlen, pos, cid, tinfo);

    int nx = B * L * D;
    int nw = 3 * D * D;
    cast_f32_bf16<<<(nx / 4 + 255) / 256, 256, 0, stream>>>(x, x_b, nx);
    cast_f32_bf16<<<(nw / 4 + 255) / 256, 256, 0, stream>>>(Wi, Wi_b, nw);
    cast_f32_bf16<<<(nw / 4 + 255) / 256, 256, 0, stream>>>(We, We_b, nw);
    cast_f32_bf16<<<(D * D / 4 + 255) / 256, 256, 0, stream>>>(Wo, Wo_b, D * D);

    dim3 gq(3 * D / 128, B * L / 128);
    gemm128<<<gq, 256, 0, stream>>>(x_b, Wi_b, bi, qkv_b, B * L, 3 * D, D, 1);
    rope_scatter2<<<B * H * NT, 256, 0, stream>>>(qkv_b, pos, q_b, k_b, vt_b);
    attn3<<<B * H * NT, 256, 0, stream>>>(q_b, k_b, vt_b, cid, tinfo, att_i, sum_b, att_i, 0);

    gemm128<<<gq, 256, 0, stream>>>(x_b, We_b, be, qkv_b, B * L, 3 * D, D, 1);
    rope_scatter2<<<B * H * NT, 256, 0, stream>>>(qkv_b, pos, q_b, k_b, vt_b);
    attn3<<<B * H * NT, 256, 0, stream>>>(q_b, k_b, vt_b, cid, tinfo, att_i, sum_b, att_i, 1);

    dim3 go(D / 128, B * L / 128);
    gemm128<<<go, 256, 0, stream>>>(sum_b, Wo_b, bo, d_out, B * L, D, D, 0);
}

// Round 2
// 440.516 us; speedup vs baseline: 1.2062x; 1.2062x over previous
//
#include <hip/hip_runtime.h>
#include <hip/hip_bf16.h>
#include <stdint.h>

#define B 2
#define L 2048
#define D 1024
#define H 16
#define HD 64
#define NT (L / 64)          // 32 tiles of 64
#define INVALID_CID 0x40000000

typedef __hip_bfloat16 bf16;
typedef __attribute__((ext_vector_type(8))) short short8;
typedef __attribute__((ext_vector_type(4))) float floatx4;
typedef __attribute__((ext_vector_type(4))) unsigned int uint4v;

static __device__ __forceinline__ short f2bf(float f) {
    bf16 h = __float2bfloat16(f);
    return *reinterpret_cast<short*>(&h);
}

// async global->LDS, 16B per lane; lptr must be wave-uniform (HW adds lane*16)
static __device__ __forceinline__ void async_copy16(const void* g, void* l) {
    __builtin_amdgcn_global_load_lds((__attribute__((address_space(1))) void*)g,
                                     (__attribute__((address_space(3))) void*)l,
                                     16, 0, 0);
}

// ---------------------------------------------------------------- chain info
__global__ void chain_kernel(const int* __restrict__ lens,
                             float* __restrict__ pos, int* __restrict__ cid,
                             int4* __restrict__ tinfo)
{
    __shared__ int csum[L];
    __shared__ int cids[L];
    __shared__ int part[256];
    int b = blockIdx.x;
    int t = threadIdx.x;

    int loc[8];
    int s = 0;
    #pragma unroll
    for (int j = 0; j < 8; ++j) { s += lens[b * L + t * 8 + j]; loc[j] = s; }
    part[t] = s;
    __syncthreads();
    if (t == 0) {
        int acc = 0;
        for (int i = 0; i < 256; ++i) { int v = part[i]; part[i] = acc; acc += v; }
    }
    __syncthreads();
    int base = part[t];
    #pragma unroll
    for (int j = 0; j < 8; ++j) csum[t * 8 + j] = base + loc[j];
    __syncthreads();

    int total = csum[L - 1];
    for (int p = t; p < L; p += 256) {
        int cv;
        if (p < total) {
            int lo = 0, hi = L;
            while (lo < hi) {
                int mid = (lo + hi) >> 1;
                if (csum[mid] <= p) lo = mid + 1; else hi = mid;
            }
            int prev = (lo > 0) ? csum[lo - 1] : 0;
            pos[b * L + p] = (float)(p - prev);
            cv = lo;
        } else {
            pos[b * L + p] = 0.f;
            cv = INVALID_CID;
        }
        cids[p] = cv;
        cid[b * L + p] = cv;
    }
    __syncthreads();
    if (t < NT) {
        int mn = 0x7fffffff, mx = -1, any = 0, all = 1;
        for (int j = 0; j < 64; ++j) {
            int cv = cids[t * 64 + j];
            if (cv != INVALID_CID) { any = 1; mn = min(mn, cv); mx = max(mx, cv); }
            else all = 0;
        }
        tinfo[b * NT + t] = make_int4(mn, mx, any | (all << 1), 0);
    }
}

// ---------------------------------------------------------------- cast
__global__ void cast_f32_bf16(const float* __restrict__ in, bf16* __restrict__ out, int n)
{
    int i = (blockIdx.x * 256 + threadIdx.x) * 4;
    if (i + 3 < n) {
        float4 v = *(const float4*)(in + i);
        out[i + 0] = __float2bfloat16(v.x);
        out[i + 1] = __float2bfloat16(v.y);
        out[i + 2] = __float2bfloat16(v.z);
        out[i + 3] = __float2bfloat16(v.w);
    } else {
        for (; i < n; ++i) out[i] = __float2bfloat16(in[i]);
    }
}

// ---------------------------------------------------------------- GEMM (m97-style)
// C = A * Bw^T + bias.  A:[M,K] bf16 rm, Bw:[N,K] bf16 rm. 128x128 tile, BK=32.
__global__ __launch_bounds__(256, 4) void gemm128(
    const bf16* __restrict__ A, const bf16* __restrict__ Bw,
    const float* __restrict__ bias, void* __restrict__ Cout,
    int M, int N, int K, int c_bf16)
{
    __shared__ short As[128 * 32];   // [row][32 shorts], 64B rows, lane-contiguous for DMA
    __shared__ short Bs[128 * 32];

    int tid = threadIdx.x;
    int wave = tid >> 6, lane = tid & 63;
    int i15 = lane & 15, q8 = lane >> 4;
    int wm = wave & 1, wn = wave >> 1;
    int m0 = blockIdx.y * 128, n0 = blockIdx.x * 128;

    floatx4 acc[4][4];
    #pragma unroll
    for (int mt = 0; mt < 4; ++mt)
        #pragma unroll
        for (int nt = 0; nt < 4; ++nt) acc[mt][nt] = (floatx4){0.f, 0.f, 0.f, 0.f};

    // wave stages rows [wave*32, wave*32+32) of A and B; lane i -> row base+i/4, chunk i%4
    const short* gA = (const short*)A  + (size_t)(m0 + wave * 32 + (lane >> 2)) * K + (lane & 3) * 8;
    const short* gB = (const short*)Bw + (size_t)(n0 + wave * 32 + (lane >> 2)) * K + (lane & 3) * 8;
    short* lA = As + wave * 1024;
    short* lB = Bs + wave * 1024;

    for (int kt = 0; kt < K; kt += 32) {
        __syncthreads();
        async_copy16(gA + kt,          lA);
        async_copy16(gA + 16 * K + kt, lA + 512);
        async_copy16(gB + kt,          lB);
        async_copy16(gB + 16 * K + kt, lB + 512);
        __syncthreads();

        short8 af[4], bfr[4];
        #pragma unroll
        for (int mt = 0; mt < 4; ++mt)
            af[mt] = *(const short8*)&As[(wm * 64 + mt * 16 + i15) * 32 + q8 * 8];
        #pragma unroll
        for (int nt = 0; nt < 4; ++nt)
            bfr[nt] = *(const short8*)&Bs[(wn * 64 + nt * 16 + i15) * 32 + q8 * 8];
        #pragma unroll
        for (int mt = 0; mt < 4; ++mt)
            #pragma unroll
            for (int nt = 0; nt < 4; ++nt)
                acc[mt][nt] = __builtin_amdgcn_mfma_f32_16x16x32_bf16(af[mt], bfr[nt], acc[mt][nt], 0, 0, 0);
    }

    #pragma unroll
    for (int nt = 0; nt < 4; ++nt) {
        int n = n0 + wn * 64 + nt * 16 + i15;
        float bv = bias[n];
        #pragma unroll
        for (int mt = 0; mt < 4; ++mt) {
            #pragma unroll
            for (int rg = 0; rg < 4; ++rg) {
                int m = m0 + wm * 64 + mt * 16 + q8 * 4 + rg;
                float v = acc[mt][nt][rg] + bv;
                if (c_bf16) ((bf16*)Cout)[(size_t)m * N + n] = __float2bfloat16(v);
                else        ((float*)Cout)[(size_t)m * N + n] = v;
            }
        }
    }
}

// ---------------------------------------------------------------- RoPE + scatter
// Q,K -> [B,H,L,HD]; V -> transposed [B,H,HD,L] via LDS transpose.
// Q additionally scaled by HD^-0.5 * log2(e)  (exp2-domain softmax downstream).
__global__ __launch_bounds__(256) void rope_scatter2(
    const bf16* __restrict__ qkv, const float* __restrict__ pos,
    bf16* __restrict__ Qo, bf16* __restrict__ Ko, bf16* __restrict__ Vtg)
{
    __shared__ float Vsh[64][65];   // conflict-free transpose staging
    int tid = threadIdx.x;
    int bid = blockIdx.x;
    int lt = bid & (NT - 1);
    int h  = (bid >> 5) & (H - 1);
    int b  = bid >> 9;
    int l0 = lt * 64;

    const float QSCALE = 0.18033688011111772f;  // 0.125 * log2(e)
    int hd = tid & 63, lq = tid >> 6;
    float sgn = (hd < 32) ? -1.f : 1.f;
    float invf = exp2f(-(float)(hd & 31) * (13.287712379549449f / 32.f));

    #pragma unroll
    for (int rr = 0; rr < 16; ++rr) {
        int l = l0 + lq * 16 + rr;
        size_t row = (size_t)(b * L + l) * (3 * D);
        int col  = h * HD + hd;
        int col2 = h * HD + (hd ^ 32);

        float xq  = __bfloat162float(qkv[row + col]);
        float xq2 = __bfloat162float(qkv[row + col2]);
        float xk  = __bfloat162float(qkv[row + D + col]);
        float xk2 = __bfloat162float(qkv[row + D + col2]);
        float xv  = __bfloat162float(qkv[row + 2 * D + col]);

        float p = pos[b * L + l];
        float ang = p * invf;
        float cc = cosf(ang), ss = sinf(ang);

        float qo = QSCALE * (xq * cc + sgn * xq2 * ss);
        float ko = xk * cc + sgn * xk2 * ss;

        size_t o = ((size_t)(b * H + h) * L + l) * HD + hd;
        Qo[o] = __float2bfloat16(qo);
        Ko[o] = __float2bfloat16(ko);
        Vsh[l - l0][hd] = xv;
    }
    __syncthreads();
    int lcol = tid & 63, dq = tid >> 6;
    #pragma unroll
    for (int rr = 0; rr < 16; ++rr) {
        int dd = dq * 16 + rr;
        Vtg[((size_t)(b * H + h) * HD + dd) * L + l0 + lcol] = __float2bfloat16(Vsh[lcol][dd]);
    }
}

// ---------------------------------------------------------------- MFMA flash attention v4
// v2 skeleton (cooperative staging + 1-tile register prefetch) with the LDS diet:
//  - S^T via operand swap: accS = mfma(K_frag, Q_frag)  (same register contents as v2)
//  - K staged at sigma-permuted LDS rows so lane's 16 P values are 2 contiguous k-octets
//    -> P assembled in-register for PV's A-operand; P NEVER touches LDS
//  - V^T fragments loaded global->reg after the barrier (L1-resident, latency covered by QK)
//  - double-buffered Ks => ONE barrier per tile; loads issued post-barrier so the
//    vmcnt(0) barrier drain never exposes them
// branch 0 (intra): allowed = key_valid && cid_q==cid_k, writes float OutF.
// branch 1 (inter): allowed = key_valid && cid_q!=cid_k, writes bf16 OutB = o + Prev.
__global__ __launch_bounds__(256, 3) void attn4(
    const bf16* __restrict__ Q, const bf16* __restrict__ Kg, const bf16* __restrict__ Vtg,
    const int* __restrict__ cid, const int4* __restrict__ tinfo,
    float* __restrict__ OutF, bf16* __restrict__ OutB, const float* __restrict__ Prev,
    int branch)
{
    __shared__ short Ks[2][64][72];
    __shared__ int cls_s[NT];
    __shared__ int list_s[NT];
    __shared__ int nlist_s;

    int tid = threadIdx.x;
    int wave = tid >> 6, lane = tid & 63;
    int i15 = lane & 15, q8 = lane >> 4;
    int bid = blockIdx.x;
    int qt = bid & (NT - 1);
    int h  = (bid >> 5) & (H - 1);
    int b  = bid >> 9;
    int q0 = qt * 64;
    const size_t bh  = (size_t)(b * H + h) * L;
    const size_t bhd = (size_t)(b * H + h) * HD;

    // Q fragments (B-operand of S^T): lane holds Q[q0+wave*16+i15][s*32+q8*8+j]
    short8 qf[2];
    {
        const short* qp = (const short*)Q + (bh + q0 + wave * 16 + i15) * HD + q8 * 8;
        qf[0] = *(const short8*)(qp);
        qf[1] = *(const short8*)(qp + 32);
    }
    int cq = cid[b * L + q0 + wave * 16 + i15];

    int4 qinf = tinfo[b * NT + qt];
    int qall = (qinf.z >> 1) & 1;

    if (tid < NT) {
        int4 ki = tinfo[b * NT + tid];
        int kany = ki.z & 1, kall = (ki.z >> 1) & 1;
        bool disjoint = (ki.x > qinf.y) || (ki.y < qinf.x);  // sentinels make !qany/!kany disjoint
        bool mono = qall && kall && (qinf.x == qinf.y) && (ki.x == ki.y) && (qinf.x == ki.x);
        int cls;
        if (branch == 0) {
            if (!kany || disjoint) cls = 0;
            else if (mono) cls = 2;
            else cls = 1;
        } else {
            if (!kany || mono) cls = 0;
            else if (kall && disjoint) cls = 2;
            else cls = 1;
        }
        cls_s[tid] = cls;
    }
    __syncthreads();
    if (tid == 0) {
        int n = 0;
        for (int t = 0; t < NT; ++t) {
            int c = cls_s[t];
            if (c) list_s[n++] = (t * 64) | ((c == 2) << 16);
        }
        nlist_s = n;
    }
    __syncthreads();
    int n = nlist_s;

    // staging geometry: thread -> K row r, 16-short chunk ccol; stored at LDS row sigma(r)
    // sigma(r) = 16*t(r) + m(r), t(r) = ((r>>2)&1) | ((r>>5)<<1), m(r) = 4*((r>>3)&3) + (r&3)
    // => reading LDS row t*16+m yields K row 32*(t>>1) + 4*(t&1) + 8*(m>>2) + (m&3)
    int r = tid >> 2, ccol = (tid & 3) * 16;
    int sr = ((((r >> 2) & 1) | ((r >> 5) << 1)) << 4) | (((r >> 3) & 3) << 2) | (r & 3);
    const short* Kbase = (const short*)Kg + (bh + r) * HD + ccol;
    const short* vb = (const short*)Vtg + (bhd + i15) * L + q8 * 8;

    int4 pk0, pk1;
    int cur = 0;
    if (n > 0) {
        cur = list_s[0];
        int kt0 = cur & 0xffff;
        pk0 = *(const int4*)(Kbase + (size_t)kt0 * HD);
        pk1 = *(const int4*)(Kbase + (size_t)kt0 * HD + 8);
    }

    floatx4 accO[4];
    #pragma unroll
    for (int t = 0; t < 4; ++t) accO[t] = (floatx4){0.f, 0.f, 0.f, 0.f};
    float lsum = 0.f;

    for (int i = 0; i < n; ++i) {
        int kt = cur & 0xffff, full = cur >> 16;

        // stage K tile i (sigma rows) into buf i&1; prefetched regs already landed
        *(int4*)&Ks[i & 1][sr][ccol]     = pk0;
        *(int4*)&Ks[i & 1][sr][ccol + 8] = pk1;
        __syncthreads();

        // post-barrier load issue: V^T frags for tile i, K stage regs for tile i+1
        short8 vf[4][2];
        #pragma unroll
        for (int dt = 0; dt < 4; ++dt)
            #pragma unroll
            for (int s = 0; s < 2; ++s)
                vf[dt][s] = *(const short8*)(vb + (size_t)dt * 16 * L + kt + s * 32);
        if (i + 1 < n) {
            cur = list_s[i + 1];
            int nk = cur & 0xffff;
            pk0 = *(const int4*)(Kbase + (size_t)nk * HD);
            pk1 = *(const int4*)(Kbase + (size_t)nk * HD + 8);
        }

        // S^T = K Q^T (log2 domain); lane's tile-t rows are k = 8*q8 + 4*(t&1) + 32*(t>>1) + rg
        unsigned int dl[4], dh[4];
        #pragma unroll
        for (int t = 0; t < 4; ++t) {
            floatx4 accS = (floatx4){0.f, 0.f, 0.f, 0.f};
            short8 b0 = *(const short8*)&Ks[i & 1][t * 16 + i15][q8 * 8];
            short8 b1 = *(const short8*)&Ks[i & 1][t * 16 + i15][32 + q8 * 8];
            accS = __builtin_amdgcn_mfma_f32_16x16x32_bf16(b0, qf[0], accS, 0, 0, 0);
            accS = __builtin_amdgcn_mfma_f32_16x16x32_bf16(b1, qf[1], accS, 0, 0, 0);

            if (!full) {
                int4 ck4 = *(const int4*)(cid + b * L + kt + (q8 << 3) + ((t & 1) << 2) + ((t >> 1) << 5));
                int ckr[4] = {ck4.x, ck4.y, ck4.z, ck4.w};
                #pragma unroll
                for (int rg = 0; rg < 4; ++rg) {
                    bool kv = (ckr[rg] != INVALID_CID);
                    bool match = (cq == ckr[rg]);
                    bool ok = kv && (branch ? !match : match);
                    accS[rg] = ok ? accS[rg] : -1e30f;
                }
            }

            float p0 = __builtin_amdgcn_exp2f(accS[0]);
            float p1 = __builtin_amdgcn_exp2f(accS[1]);
            float p2 = __builtin_amdgcn_exp2f(accS[2]);
            float p3 = __builtin_amdgcn_exp2f(accS[3]);
            lsum += (p0 + p1) + (p2 + p3);
            dl[t] = (unsigned int)(unsigned short)f2bf(p0) | ((unsigned int)(unsigned short)f2bf(p1) << 16);
            dh[t] = (unsigned int)(unsigned short)f2bf(p2) | ((unsigned int)(unsigned short)f2bf(p3) << 16);
        }

        // P A-fragments assembled in-register:
        //   pa0 covers k = 8*q8 + 0..7  (tiles 0,1), pa1 covers k = 32 + 8*q8 + 0..7 (tiles 2,3)
        union { uint4v u; short8 s; } pa0, pa1;
        pa0.u = (uint4v){dl[0], dh[0], dl[1], dh[1]};
        pa1.u = (uint4v){dl[2], dh[2], dl[3], dh[3]};

        // O += P V  (B = V^T frags from registers)
        #pragma unroll
        for (int dt = 0; dt < 4; ++dt) {
            accO[dt] = __builtin_amdgcn_mfma_f32_16x16x32_bf16(pa0.s, vf[dt][0], accO[dt], 0, 0, 0);
            accO[dt] = __builtin_amdgcn_mfma_f32_16x16x32_bf16(pa1.s, vf[dt][1], accO[dt], 0, 0, 0);
        }
    }

    // row-sum: lane holds partial for q-col i15; reduce across the 4 lane-groups
    lsum += __shfl_xor(lsum, 16, 64);
    lsum += __shfl_xor(lsum, 32, 64);
    float inv[4];
    #pragma unroll
    for (int rg = 0; rg < 4; ++rg) {
        float ls = __shfl(lsum, q8 * 4 + rg, 64);   // lanes 0..15 hold q-locals 0..15
        inv[rg] = (ls > 0.f) ? 1.f / ls : 0.f;
    }

    #pragma unroll
    for (int t = 0; t < 4; ++t) {
        #pragma unroll
        for (int rg = 0; rg < 4; ++rg) {
            size_t idx = (size_t)(b * L + q0 + wave * 16 + q8 * 4 + rg) * D + h * HD + t * 16 + i15;
            float o = accO[t][rg] * inv[rg];
            if (branch == 0) OutF[idx] = o;
            else             OutB[idx] = __float2bfloat16(o + Prev[idx]);
        }
    }
}

// ---------------------------------------------------------------- launch
extern "C" void kernel_launch(void* const* d_in, const int* in_sizes, int n_in,
                              void* d_out, int out_size, void* d_ws, size_t ws_size,
                              hipStream_t stream)
{
    const float* x    = (const float*)d_in[0];
    const int*   mlen = (const int*)  d_in[1];
    const float* Wi   = (const float*)d_in[2];
    const float* bi   = (const float*)d_in[3];
    const float* We   = (const float*)d_in[4];
    const float* be   = (const float*)d_in[5];
    const float* Wo   = (const float*)d_in[6];
    const float* bo   = (const float*)d_in[7];

    char* ws = (char*)d_ws;
    size_t off = 0;
    auto alloc = [&](size_t bytes) {
        void* p = ws + off;
        off += (bytes + 255) & ~(size_t)255;
        return p;
    };
    bf16*  x_b   = (bf16*) alloc((size_t)B * L * D * 2);
    bf16*  Wi_b  = (bf16*) alloc((size_t)3 * D * D * 2);
    bf16*  We_b  = (bf16*) alloc((size_t)3 * D * D * 2);
    bf16*  Wo_b  = (bf16*) alloc((size_t)D * D * 2);
    bf16*  qkv_b = (bf16*) alloc((size_t)B * L * 3 * D * 2);
    bf16*  q_b   = (bf16*) alloc((size_t)B * H * L * HD * 2);
    bf16*  k_b   = (bf16*) alloc((size_t)B * H * L * HD * 2);
    bf16*  vt_b  = (bf16*) alloc((size_t)B * H * HD * L * 2);
    float* att_i = (float*)alloc((size_t)B * L * D * 4);
    bf16*  sum_b = (bf16*) alloc((size_t)B * L * D * 2);
    float* pos   = (float*)alloc((size_t)B * L * 4);
    int*   cid   = (int*)  alloc((size_t)B * L * 4);
    int4*  tinfo = (int4*) alloc((size_t)B * NT * 16);
    (void)ws_size; (void)n_in; (void)in_sizes; (void)out_size;

    chain_kernel<<<B, 256, 0, stream>>>(mlen, pos, cid, tinfo);

    int nx = B * L * D;
    int nw = 3 * D * D;
    cast_f32_bf16<<<(nx / 4 + 255) / 256, 256, 0, stream>>>(x, x_b, nx);
    cast_f32_bf16<<<(nw / 4 + 255) / 256, 256, 0, stream>>>(Wi, Wi_b, nw);
    cast_f32_bf16<<<(nw / 4 + 255) / 256, 256, 0, stream>>>(We, We_b, nw);
    cast_f32_bf16<<<(D * D / 4 + 255) / 256, 256, 0, stream>>>(Wo, Wo_b, D * D);

    dim3 gq(3 * D / 128, B * L / 128);
    gemm128<<<gq, 256, 0, stream>>>(x_b, Wi_b, bi, qkv_b, B * L, 3 * D, D, 1);
    rope_scatter2<<<B * H * NT, 256, 0, stream>>>(qkv_b, pos, q_b, k_b, vt_b);
    attn4<<<B * H * NT, 256, 0, stream>>>(q_b, k_b, vt_b, cid, tinfo, att_i, sum_b, att_i, 0);

    gemm128<<<gq, 256, 0, stream>>>(x_b, We_b, be, qkv_b, B * L, 3 * D, D, 1);
    rope_scatter2<<<B * H * NT, 256, 0, stream>>>(qkv_b, pos, q_b, k_b, vt_b);
    attn4<<<B * H * NT, 256, 0, stream>>>(q_b, k_b, vt_b, cid, tinfo, att_i, sum_b, att_i, 1);

    dim3 go(D / 128, B * L / 128);
    gemm128<<<go, 256, 0, stream>>>(sum_b, Wo_b, bo, d_out, B * L, D, D, 0);
}

// Round 3
// 337.300 us; speedup vs baseline: 1.5753x; 1.3060x over previous
//
#include <hip/hip_runtime.h>
#include <hip/hip_bf16.h>
#include <stdint.h>

#define B 2
#define L 2048
#define D 1024
#define H 16
#define HD 64
#define NT (L / 64)          // 32 tiles of 64
#define INVALID_CID 0x40000000

typedef __hip_bfloat16 bf16;
typedef __attribute__((ext_vector_type(8))) short short8;
typedef __attribute__((ext_vector_type(4))) float floatx4;
typedef __attribute__((ext_vector_type(4))) unsigned int uint4v;

static __device__ __forceinline__ short f2bf(float f) {
    bf16 h = __float2bfloat16(f);
    return *reinterpret_cast<short*>(&h);
}

// async global->LDS, 16B per lane; lptr must be wave-uniform (HW adds lane*16)
static __device__ __forceinline__ void async_copy16(const void* g, void* l) {
    __builtin_amdgcn_global_load_lds((__attribute__((address_space(1))) void*)g,
                                     (__attribute__((address_space(3))) void*)l,
                                     16, 0, 0);
}

// ---------------------------------------------------------------- chain info
__global__ void chain_kernel(const int* __restrict__ lens,
                             float* __restrict__ pos, int* __restrict__ cid,
                             int4* __restrict__ tinfo)
{
    __shared__ int csum[L];
    __shared__ int cids[L];
    __shared__ int part[256];
    int b = blockIdx.x;
    int t = threadIdx.x;

    int loc[8];
    int s = 0;
    #pragma unroll
    for (int j = 0; j < 8; ++j) { s += lens[b * L + t * 8 + j]; loc[j] = s; }
    part[t] = s;
    __syncthreads();
    if (t == 0) {
        int acc = 0;
        for (int i = 0; i < 256; ++i) { int v = part[i]; part[i] = acc; acc += v; }
    }
    __syncthreads();
    int base = part[t];
    #pragma unroll
    for (int j = 0; j < 8; ++j) csum[t * 8 + j] = base + loc[j];
    __syncthreads();

    int total = csum[L - 1];
    for (int p = t; p < L; p += 256) {
        int cv;
        if (p < total) {
            int lo = 0, hi = L;
            while (lo < hi) {
                int mid = (lo + hi) >> 1;
                if (csum[mid] <= p) lo = mid + 1; else hi = mid;
            }
            int prev = (lo > 0) ? csum[lo - 1] : 0;
            pos[b * L + p] = (float)(p - prev);
            cv = lo;
        } else {
            pos[b * L + p] = 0.f;
            cv = INVALID_CID;
        }
        cids[p] = cv;
        cid[b * L + p] = cv;
    }
    __syncthreads();
    if (t < NT) {
        int mn = 0x7fffffff, mx = -1, any = 0, all = 1;
        for (int j = 0; j < 64; ++j) {
            int cv = cids[t * 64 + j];
            if (cv != INVALID_CID) { any = 1; mn = min(mn, cv); mx = max(mx, cv); }
            else all = 0;
        }
        tinfo[b * NT + t] = make_int4(mn, mx, any | (all << 1), 0);
    }
}

// ---------------------------------------------------------------- fused casts
// segments (1024 floats per block): x:4096 | Wi:3072 | We:3072 | Wo:1024  (all exact)
__global__ void cast_all(const float* __restrict__ x,  const float* __restrict__ Wi,
                         const float* __restrict__ We, const float* __restrict__ Wo,
                         bf16* __restrict__ xb, bf16* __restrict__ Wib,
                         bf16* __restrict__ Web, bf16* __restrict__ Wob)
{
    int bid = blockIdx.x;
    const float* src; bf16* dst; int base;
    if      (bid < 4096)  { src = x;  dst = xb;  base = bid; }
    else if (bid < 7168)  { src = Wi; dst = Wib; base = bid - 4096; }
    else if (bid < 10240) { src = We; dst = Web; base = bid - 7168; }
    else                  { src = Wo; dst = Wob; base = bid - 10240; }
    int i = (base * 256 + threadIdx.x) * 4;
    float4 v = *(const float4*)(src + i);
    dst[i + 0] = __float2bfloat16(v.x);
    dst[i + 1] = __float2bfloat16(v.y);
    dst[i + 2] = __float2bfloat16(v.z);
    dst[i + 3] = __float2bfloat16(v.w);
}

// ---------------------------------------------------------------- GEMM (m97-style)
// C = A * Bw^T + bias.  A:[M,K] bf16 rm, Bw:[N,K] bf16 rm. 128x128 tile, BK=32.
__global__ __launch_bounds__(256, 4) void gemm128(
    const bf16* __restrict__ A, const bf16* __restrict__ Bw,
    const float* __restrict__ bias, void* __restrict__ Cout,
    int M, int N, int K, int c_bf16)
{
    __shared__ short As[128 * 32];   // [row][32 shorts], 64B rows, lane-contiguous for DMA
    __shared__ short Bs[128 * 32];

    int tid = threadIdx.x;
    int wave = tid >> 6, lane = tid & 63;
    int i15 = lane & 15, q8 = lane >> 4;
    int wm = wave & 1, wn = wave >> 1;
    int m0 = blockIdx.y * 128, n0 = blockIdx.x * 128;

    floatx4 acc[4][4];
    #pragma unroll
    for (int mt = 0; mt < 4; ++mt)
        #pragma unroll
        for (int nt = 0; nt < 4; ++nt) acc[mt][nt] = (floatx4){0.f, 0.f, 0.f, 0.f};

    // wave stages rows [wave*32, wave*32+32) of A and B; lane i -> row base+i/4, chunk i%4
    const short* gA = (const short*)A  + (size_t)(m0 + wave * 32 + (lane >> 2)) * K + (lane & 3) * 8;
    const short* gB = (const short*)Bw + (size_t)(n0 + wave * 32 + (lane >> 2)) * K + (lane & 3) * 8;
    short* lA = As + wave * 1024;
    short* lB = Bs + wave * 1024;

    for (int kt = 0; kt < K; kt += 32) {
        __syncthreads();
        async_copy16(gA + kt,          lA);
        async_copy16(gA + 16 * K + kt, lA + 512);
        async_copy16(gB + kt,          lB);
        async_copy16(gB + 16 * K + kt, lB + 512);
        __syncthreads();

        short8 af[4], bfr[4];
        #pragma unroll
        for (int mt = 0; mt < 4; ++mt)
            af[mt] = *(const short8*)&As[(wm * 64 + mt * 16 + i15) * 32 + q8 * 8];
        #pragma unroll
        for (int nt = 0; nt < 4; ++nt)
            bfr[nt] = *(const short8*)&Bs[(wn * 64 + nt * 16 + i15) * 32 + q8 * 8];
        #pragma unroll
        for (int mt = 0; mt < 4; ++mt)
            #pragma unroll
            for (int nt = 0; nt < 4; ++nt)
                acc[mt][nt] = __builtin_amdgcn_mfma_f32_16x16x32_bf16(af[mt], bfr[nt], acc[mt][nt], 0, 0, 0);
    }

    #pragma unroll
    for (int nt = 0; nt < 4; ++nt) {
        int n = n0 + wn * 64 + nt * 16 + i15;
        float bv = bias[n];
        #pragma unroll
        for (int mt = 0; mt < 4; ++mt) {
            #pragma unroll
            for (int rg = 0; rg < 4; ++rg) {
                int m = m0 + wm * 64 + mt * 16 + q8 * 4 + rg;
                float v = acc[mt][nt][rg] + bv;
                if (c_bf16) ((bf16*)Cout)[(size_t)m * N + n] = __float2bfloat16(v);
                else        ((float*)Cout)[(size_t)m * N + n] = v;
            }
        }
    }
}

// ---------------------------------------------------------------- RoPE + scatter
// Q,K -> [B,H,L,HD]; V -> transposed [B,H,HD,L] via LDS transpose.
// Q additionally scaled by HD^-0.5 * log2(e)  (exp2-domain softmax downstream).
__global__ __launch_bounds__(256) void rope_scatter2(
    const bf16* __restrict__ qkv, const float* __restrict__ pos,
    bf16* __restrict__ Qo, bf16* __restrict__ Ko, bf16* __restrict__ Vtg)
{
    __shared__ float Vsh[64][65];   // conflict-free transpose staging
    int tid = threadIdx.x;
    int bid = blockIdx.x;
    int lt = bid & (NT - 1);
    int h  = (bid >> 5) & (H - 1);
    int b  = bid >> 9;
    int l0 = lt * 64;

    const float QSCALE = 0.18033688011111772f;  // 0.125 * log2(e)
    int hd = tid & 63, lq = tid >> 6;
    float sgn = (hd < 32) ? -1.f : 1.f;
    float invf = exp2f(-(float)(hd & 31) * (13.287712379549449f / 32.f));

    #pragma unroll
    for (int rr = 0; rr < 16; ++rr) {
        int l = l0 + lq * 16 + rr;
        size_t row = (size_t)(b * L + l) * (3 * D);
        int col  = h * HD + hd;
        int col2 = h * HD + (hd ^ 32);

        float xq  = __bfloat162float(qkv[row + col]);
        float xq2 = __bfloat162float(qkv[row + col2]);
        float xk  = __bfloat162float(qkv[row + D + col]);
        float xk2 = __bfloat162float(qkv[row + D + col2]);
        float xv  = __bfloat162float(qkv[row + 2 * D + col]);

        float p = pos[b * L + l];
        float ang = p * invf;
        float cc = cosf(ang), ss = sinf(ang);

        float qo = QSCALE * (xq * cc + sgn * xq2 * ss);
        float ko = xk * cc + sgn * xk2 * ss;

        size_t o = ((size_t)(b * H + h) * L + l) * HD + hd;
        Qo[o] = __float2bfloat16(qo);
        Ko[o] = __float2bfloat16(ko);
        Vsh[l - l0][hd] = xv;
    }
    __syncthreads();
    int lcol = tid & 63, dq = tid >> 6;
    #pragma unroll
    for (int rr = 0; rr < 16; ++rr) {
        int dd = dq * 16 + rr;
        Vtg[((size_t)(b * H + h) * HD + dd) * L + l0 + lcol] = __float2bfloat16(Vsh[lcol][dd]);
    }
}

// ---------------------------------------------------------------- MFMA flash attention v5
// = v2's proven pipeline (cooperative coalesced K+V staging, 1-tile register prefetch)
// + v4's verified sigma-permuted K rows / operand-swapped QK^T => P stays in registers
// + double-buffered LDS => ONE barrier per tile
// + XCD-aware block swizzle (1024 blocks % 8 == 0): each XCD's L2 sees only 4 heads'
//   K/V (~2.2 MB < 4 MB) instead of all 16.8 MB.
// branch 0 (intra): allowed = key_valid && cid_q==cid_k, writes float OutF.
// branch 1 (inter): allowed = key_valid && cid_q!=cid_k, writes bf16 OutB = o + Prev.
__global__ __launch_bounds__(256, 4) void attn5(
    const bf16* __restrict__ Q, const bf16* __restrict__ Kg, const bf16* __restrict__ Vtg,
    const int* __restrict__ cid, const int4* __restrict__ tinfo,
    float* __restrict__ OutF, bf16* __restrict__ OutB, const float* __restrict__ Prev,
    int branch)
{
    __shared__ short Ks[2][64][72];
    __shared__ short Vs[2][64][72];   // V^T tile: [dim][key]
    __shared__ int cls_s[NT];
    __shared__ int list_s[NT];
    __shared__ int nlist_s;

    int tid = threadIdx.x;
    int wave = tid >> 6, lane = tid & 63;
    int i15 = lane & 15, q8 = lane >> 4;
    // XCD swizzle: hw-block -> work id so each XCD gets 128 contiguous work ids
    int workid = ((blockIdx.x & 7) << 7) | (blockIdx.x >> 3);
    int qt = workid & (NT - 1);
    int h  = (workid >> 5) & (H - 1);
    int b  = workid >> 9;
    int q0 = qt * 64;
    const size_t bh  = (size_t)(b * H + h) * L;
    const size_t bhd = (size_t)(b * H + h) * HD;

    // Q fragments (B-operand of S^T): lane holds Q[q0+wave*16+i15][s*32+q8*8+j]
    short8 qf[2];
    {
        const short* qp = (const short*)Q + (bh + q0 + wave * 16 + i15) * HD + q8 * 8;
        qf[0] = *(const short8*)(qp);
        qf[1] = *(const short8*)(qp + 32);
    }
    int cq = cid[b * L + q0 + wave * 16 + i15];

    int4 qinf = tinfo[b * NT + qt];
    int qall = (qinf.z >> 1) & 1;

    if (tid < NT) {
        int4 ki = tinfo[b * NT + tid];
        int kany = ki.z & 1, kall = (ki.z >> 1) & 1;
        bool disjoint = (ki.x > qinf.y) || (ki.y < qinf.x);  // sentinels make !qany/!kany disjoint
        bool mono = qall && kall && (qinf.x == qinf.y) && (ki.x == ki.y) && (qinf.x == ki.x);
        int cls;
        if (branch == 0) {
            if (!kany || disjoint) cls = 0;
            else if (mono) cls = 2;
            else cls = 1;
        } else {
            if (!kany || mono) cls = 0;
            else if (kall && disjoint) cls = 2;
            else cls = 1;
        }
        cls_s[tid] = cls;
    }
    __syncthreads();
    if (tid == 0) {
        int n = 0;
        for (int t = 0; t < NT; ++t) {
            int c = cls_s[t];
            if (c) list_s[n++] = (t * 64) | ((c == 2) << 16);
        }
        nlist_s = n;
    }
    __syncthreads();
    int n = nlist_s;

    // staging geometry: thread -> row r, 16-short chunk ccol.
    // K stored at LDS row sigma(r) = 16*t(r)+m(r), t(r)=((r>>2)&1)|((r>>5)<<1),
    // m(r)=4*((r>>3)&3)+(r&3); reading row t*16+m yields K row (m&3)+4*(t&1)+8*(m>>2)+32*(t>>1).
    // V stored at plain row r (V^T: [dim][key]).
    int r = tid >> 2, ccol = (tid & 3) * 16;
    int sr = ((((r >> 2) & 1) | ((r >> 5) << 1)) << 4) | (((r >> 3) & 3) << 2) | (r & 3);
    const short* Kbase = (const short*)Kg  + (bh + r) * HD + ccol;
    const short* Vbase = (const short*)Vtg + (bhd + r) * L + ccol;

    int4 pk0, pk1, pv0, pv1;
    int cur = 0;
    if (n > 0) {
        cur = list_s[0];
        int kt0 = cur & 0xffff;
        pk0 = *(const int4*)(Kbase + (size_t)kt0 * HD);
        pk1 = *(const int4*)(Kbase + (size_t)kt0 * HD + 8);
        pv0 = *(const int4*)(Vbase + kt0);
        pv1 = *(const int4*)(Vbase + kt0 + 8);
    }

    floatx4 accO[4];
    #pragma unroll
    for (int t = 0; t < 4; ++t) accO[t] = (floatx4){0.f, 0.f, 0.f, 0.f};
    float lsum = 0.f;

    for (int i = 0; i < n; ++i) {
        int kt = cur & 0xffff, full = cur >> 16;
        int buf = i & 1;

        // stage tile i (prefetched regs already landed)
        *(int4*)&Ks[buf][sr][ccol]     = pk0;
        *(int4*)&Ks[buf][sr][ccol + 8] = pk1;
        *(int4*)&Vs[buf][r][ccol]      = pv0;
        *(int4*)&Vs[buf][r][ccol + 8]  = pv1;
        __syncthreads();

        // post-barrier: issue next tile's prefetch (covered by this tile's compute)
        if (i + 1 < n) {
            cur = list_s[i + 1];
            int nk = cur & 0xffff;
            pk0 = *(const int4*)(Kbase + (size_t)nk * HD);
            pk1 = *(const int4*)(Kbase + (size_t)nk * HD + 8);
            pv0 = *(const int4*)(Vbase + nk);
            pv1 = *(const int4*)(Vbase + nk + 8);
        }

        // S^T = K Q^T (log2 domain); lane's tile-t rows are k = 8*q8 + 4*(t&1) + 32*(t>>1) + rg
        unsigned int dl[4], dh[4];
        #pragma unroll
        for (int t = 0; t < 4; ++t) {
            floatx4 accS = (floatx4){0.f, 0.f, 0.f, 0.f};
            short8 b0 = *(const short8*)&Ks[buf][t * 16 + i15][q8 * 8];
            short8 b1 = *(const short8*)&Ks[buf][t * 16 + i15][32 + q8 * 8];
            accS = __builtin_amdgcn_mfma_f32_16x16x32_bf16(b0, qf[0], accS, 0, 0, 0);
            accS = __builtin_amdgcn_mfma_f32_16x16x32_bf16(b1, qf[1], accS, 0, 0, 0);

            if (!full) {
                int4 ck4 = *(const int4*)(cid + b * L + kt + (q8 << 3) + ((t & 1) << 2) + ((t >> 1) << 5));
                int ckr[4] = {ck4.x, ck4.y, ck4.z, ck4.w};
                #pragma unroll
                for (int rg = 0; rg < 4; ++rg) {
                    bool kv = (ckr[rg] != INVALID_CID);
                    bool match = (cq == ckr[rg]);
                    bool ok = kv && (branch ? !match : match);
                    accS[rg] = ok ? accS[rg] : -1e30f;
                }
            }

            float p0 = __builtin_amdgcn_exp2f(accS[0]);
            float p1 = __builtin_amdgcn_exp2f(accS[1]);
            float p2 = __builtin_amdgcn_exp2f(accS[2]);
            float p3 = __builtin_amdgcn_exp2f(accS[3]);
            lsum += (p0 + p1) + (p2 + p3);
            dl[t] = (unsigned int)(unsigned short)f2bf(p0) | ((unsigned int)(unsigned short)f2bf(p1) << 16);
            dh[t] = (unsigned int)(unsigned short)f2bf(p2) | ((unsigned int)(unsigned short)f2bf(p3) << 16);
        }

        // P A-fragments in-register: pa0 -> k = 8*q8 + 0..7, pa1 -> k = 32 + 8*q8 + 0..7
        union { uint4v u; short8 s; } pa0, pa1;
        pa0.u = (uint4v){dl[0], dh[0], dl[1], dh[1]};
        pa1.u = (uint4v){dl[2], dh[2], dl[3], dh[3]};

        // O += P V  (B = V^T frags from LDS, read interleaved with the MFMAs)
        #pragma unroll
        for (int dt = 0; dt < 4; ++dt) {
            short8 vf0 = *(const short8*)&Vs[buf][dt * 16 + i15][q8 * 8];
            short8 vf1 = *(const short8*)&Vs[buf][dt * 16 + i15][32 + q8 * 8];
            accO[dt] = __builtin_amdgcn_mfma_f32_16x16x32_bf16(pa0.s, vf0, accO[dt], 0, 0, 0);
            accO[dt] = __builtin_amdgcn_mfma_f32_16x16x32_bf16(pa1.s, vf1, accO[dt], 0, 0, 0);
        }
    }

    // row-sum: lane holds partial for q-col i15; reduce across the 4 lane-groups
    lsum += __shfl_xor(lsum, 16, 64);
    lsum += __shfl_xor(lsum, 32, 64);
    float inv[4];
    #pragma unroll
    for (int rg = 0; rg < 4; ++rg) {
        float ls = __shfl(lsum, q8 * 4 + rg, 64);   // lanes 0..15 hold q-locals 0..15
        inv[rg] = (ls > 0.f) ? 1.f / ls : 0.f;
    }

    #pragma unroll
    for (int t = 0; t < 4; ++t) {
        #pragma unroll
        for (int rg = 0; rg < 4; ++rg) {
            size_t idx = (size_t)(b * L + q0 + wave * 16 + q8 * 4 + rg) * D + h * HD + t * 16 + i15;
            float o = accO[t][rg] * inv[rg];
            if (branch == 0) OutF[idx] = o;
            else             OutB[idx] = __float2bfloat16(o + Prev[idx]);
        }
    }
}

// ---------------------------------------------------------------- launch
extern "C" void kernel_launch(void* const* d_in, const int* in_sizes, int n_in,
                              void* d_out, int out_size, void* d_ws, size_t ws_size,
                              hipStream_t stream)
{
    const float* x    = (const float*)d_in[0];
    const int*   mlen = (const int*)  d_in[1];
    const float* Wi   = (const float*)d_in[2];
    const float* bi   = (const float*)d_in[3];
    const float* We   = (const float*)d_in[4];
    const float* be   = (const float*)d_in[5];
    const float* Wo   = (const float*)d_in[6];
    const float* bo   = (const float*)d_in[7];

    char* ws = (char*)d_ws;
    size_t off = 0;
    auto alloc = [&](size_t bytes) {
        void* p = ws + off;
        off += (bytes + 255) & ~(size_t)255;
        return p;
    };
    bf16*  x_b   = (bf16*) alloc((size_t)B * L * D * 2);
    bf16*  Wi_b  = (bf16*) alloc((size_t)3 * D * D * 2);
    bf16*  We_b  = (bf16*) alloc((size_t)3 * D * D * 2);
    bf16*  Wo_b  = (bf16*) alloc((size_t)D * D * 2);
    bf16*  qkv_b = (bf16*) alloc((size_t)B * L * 3 * D * 2);
    bf16*  q_b   = (bf16*) alloc((size_t)B * H * L * HD * 2);
    bf16*  k_b   = (bf16*) alloc((size_t)B * H * L * HD * 2);
    bf16*  vt_b  = (bf16*) alloc((size_t)B * H * HD * L * 2);
    float* att_i = (float*)alloc((size_t)B * L * D * 4);
    bf16*  sum_b = (bf16*) alloc((size_t)B * L * D * 2);
    float* pos   = (float*)alloc((size_t)B * L * 4);
    int*   cid   = (int*)  alloc((size_t)B * L * 4);
    int4*  tinfo = (int4*) alloc((size_t)B * NT * 16);
    (void)ws_size; (void)n_in; (void)in_sizes; (void)out_size;

    chain_kernel<<<B, 256, 0, stream>>>(mlen, pos, cid, tinfo);

    // fused bf16 casts: x(4096 blk) | Wi(3072) | We(3072) | Wo(1024)
    cast_all<<<11264, 256, 0, stream>>>(x, Wi, We, Wo, x_b, Wi_b, We_b, Wo_b);

    dim3 gq(3 * D / 128, B * L / 128);
    gemm128<<<gq, 256, 0, stream>>>(x_b, Wi_b, bi, qkv_b, B * L, 3 * D, D, 1);
    rope_scatter2<<<B * H * NT, 256, 0, stream>>>(qkv_b, pos, q_b, k_b, vt_b);
    attn5<<<B * H * NT, 256, 0, stream>>>(q_b, k_b, vt_b, cid, tinfo, att_i, sum_b, att_i, 0);

    gemm128<<<gq, 256, 0, stream>>>(x_b, We_b, be, qkv_b, B * L, 3 * D, D, 1);
    rope_scatter2<<<B * H * NT, 256, 0, stream>>>(qkv_b, pos, q_b, k_b, vt_b);
    attn5<<<B * H * NT, 256, 0, stream>>>(q_b, k_b, vt_b, cid, tinfo, att_i, sum_b, att_i, 1);

    dim3 go(D / 128, B * L / 128);
    gemm128<<<go, 256, 0, stream>>>(sum_b, Wo_b, bo, d_out, B * L, D, D, 0);
}

// Round 4
// 331.807 us; speedup vs baseline: 1.6014x; 1.0166x over previous
//
#include <hip/hip_runtime.h>
#include <hip/hip_bf16.h>
#include <stdint.h>

#define B 2
#define L 2048
#define D 1024
#define H 16
#define HD 64
#define NT (L / 64)          // 32 k-tiles of 64
#define NQT (L / 128)        // 16 q-tiles of 128
#define INVALID_CID 0x40000000

typedef __hip_bfloat16 bf16;
typedef __attribute__((ext_vector_type(8))) short short8;
typedef __attribute__((ext_vector_type(4))) float floatx4;
typedef __attribute__((ext_vector_type(4))) unsigned int uint4v;

static __device__ __forceinline__ short f2bf(float f) {
    bf16 h = __float2bfloat16(f);
    return *reinterpret_cast<short*>(&h);
}

// async global->LDS, 16B per lane; lptr must be wave-uniform (HW adds lane*16)
static __device__ __forceinline__ void async_copy16(const void* g, void* l) {
    __builtin_amdgcn_global_load_lds((__attribute__((address_space(1))) void*)g,
                                     (__attribute__((address_space(3))) void*)l,
                                     16, 0, 0);
}

// ---------------------------------------------------------------- chain info
__global__ void chain_kernel(const int* __restrict__ lens,
                             float* __restrict__ pos, int* __restrict__ cid,
                             int4* __restrict__ tinfo)
{
    __shared__ int csum[L];
    __shared__ int cids[L];
    __shared__ int part[256];
    int b = blockIdx.x;
    int t = threadIdx.x;

    int loc[8];
    int s = 0;
    #pragma unroll
    for (int j = 0; j < 8; ++j) { s += lens[b * L + t * 8 + j]; loc[j] = s; }
    part[t] = s;
    __syncthreads();
    if (t == 0) {
        int acc = 0;
        for (int i = 0; i < 256; ++i) { int v = part[i]; part[i] = acc; acc += v; }
    }
    __syncthreads();
    int base = part[t];
    #pragma unroll
    for (int j = 0; j < 8; ++j) csum[t * 8 + j] = base + loc[j];
    __syncthreads();

    int total = csum[L - 1];
    for (int p = t; p < L; p += 256) {
        int cv;
        if (p < total) {
            int lo = 0, hi = L;
            while (lo < hi) {
                int mid = (lo + hi) >> 1;
                if (csum[mid] <= p) lo = mid + 1; else hi = mid;
            }
            int prev = (lo > 0) ? csum[lo - 1] : 0;
            pos[b * L + p] = (float)(p - prev);
            cv = lo;
        } else {
            pos[b * L + p] = 0.f;
            cv = INVALID_CID;
        }
        cids[p] = cv;
        cid[b * L + p] = cv;
    }
    __syncthreads();
    if (t < NT) {
        int mn = 0x7fffffff, mx = -1, any = 0, all = 1;
        for (int j = 0; j < 64; ++j) {
            int cv = cids[t * 64 + j];
            if (cv != INVALID_CID) { any = 1; mn = min(mn, cv); mx = max(mx, cv); }
            else all = 0;
        }
        tinfo[b * NT + t] = make_int4(mn, mx, any | (all << 1), 0);
    }
}

// ---------------------------------------------------------------- fused casts
// segments (1024 floats per block): x:4096 | Wi:3072 | We:3072 | Wo:1024  (all exact)
__global__ void cast_all(const float* __restrict__ x,  const float* __restrict__ Wi,
                         const float* __restrict__ We, const float* __restrict__ Wo,
                         bf16* __restrict__ xb, bf16* __restrict__ Wib,
                         bf16* __restrict__ Web, bf16* __restrict__ Wob)
{
    int bid = blockIdx.x;
    const float* src; bf16* dst; int base;
    if      (bid < 4096)  { src = x;  dst = xb;  base = bid; }
    else if (bid < 7168)  { src = Wi; dst = Wib; base = bid - 4096; }
    else if (bid < 10240) { src = We; dst = Web; base = bid - 7168; }
    else                  { src = Wo; dst = Wob; base = bid - 10240; }
    int i = (base * 256 + threadIdx.x) * 4;
    float4 v = *(const float4*)(src + i);
    dst[i + 0] = __float2bfloat16(v.x);
    dst[i + 1] = __float2bfloat16(v.y);
    dst[i + 2] = __float2bfloat16(v.z);
    dst[i + 3] = __float2bfloat16(v.w);
}

// ---------------------------------------------------------------- GEMM (m97-style)
// C = A * Bw^T + bias.  A:[M,K] bf16 rm, Bw:[N,K] bf16 rm. 128x128 tile, BK=32.
// bias split: col n uses bias[n] if n<nsplit else bias2[n-nsplit].
__global__ __launch_bounds__(256, 4) void gemm128(
    const bf16* __restrict__ A, const bf16* __restrict__ Bw,
    const float* __restrict__ bias, const float* __restrict__ bias2,
    void* __restrict__ Cout, int M, int N, int K, int c_bf16, int nsplit)
{
    __shared__ short As[128 * 32];   // [row][32 shorts], 64B rows, lane-contiguous for DMA
    __shared__ short Bs[128 * 32];

    int tid = threadIdx.x;
    int wave = tid >> 6, lane = tid & 63;
    int i15 = lane & 15, q8 = lane >> 4;
    int wm = wave & 1, wn = wave >> 1;
    int m0 = blockIdx.y * 128, n0 = blockIdx.x * 128;

    floatx4 acc[4][4];
    #pragma unroll
    for (int mt = 0; mt < 4; ++mt)
        #pragma unroll
        for (int nt = 0; nt < 4; ++nt) acc[mt][nt] = (floatx4){0.f, 0.f, 0.f, 0.f};

    // wave stages rows [wave*32, wave*32+32) of A and B; lane i -> row base+i/4, chunk i%4
    const short* gA = (const short*)A  + (size_t)(m0 + wave * 32 + (lane >> 2)) * K + (lane & 3) * 8;
    const short* gB = (const short*)Bw + (size_t)(n0 + wave * 32 + (lane >> 2)) * K + (lane & 3) * 8;
    short* lA = As + wave * 1024;
    short* lB = Bs + wave * 1024;

    for (int kt = 0; kt < K; kt += 32) {
        __syncthreads();
        async_copy16(gA + kt,          lA);
        async_copy16(gA + 16 * K + kt, lA + 512);
        async_copy16(gB + kt,          lB);
        async_copy16(gB + 16 * K + kt, lB + 512);
        __syncthreads();

        short8 af[4], bfr[4];
        #pragma unroll
        for (int mt = 0; mt < 4; ++mt)
            af[mt] = *(const short8*)&As[(wm * 64 + mt * 16 + i15) * 32 + q8 * 8];
        #pragma unroll
        for (int nt = 0; nt < 4; ++nt)
            bfr[nt] = *(const short8*)&Bs[(wn * 64 + nt * 16 + i15) * 32 + q8 * 8];
        #pragma unroll
        for (int mt = 0; mt < 4; ++mt)
            #pragma unroll
            for (int nt = 0; nt < 4; ++nt)
                acc[mt][nt] = __builtin_amdgcn_mfma_f32_16x16x32_bf16(af[mt], bfr[nt], acc[mt][nt], 0, 0, 0);
    }

    #pragma unroll
    for (int nt = 0; nt < 4; ++nt) {
        int n = n0 + wn * 64 + nt * 16 + i15;
        float bv = (n < nsplit) ? bias[n] : bias2[n - nsplit];
        #pragma unroll
        for (int mt = 0; mt < 4; ++mt) {
            #pragma unroll
            for (int rg = 0; rg < 4; ++rg) {
                int m = m0 + wm * 64 + mt * 16 + q8 * 4 + rg;
                float v = acc[mt][nt][rg] + bv;
                if (c_bf16) ((bf16*)Cout)[(size_t)m * N + n] = __float2bfloat16(v);
                else        ((float*)Cout)[(size_t)m * N + n] = v;
            }
        }
    }
}

// ---------------------------------------------------------------- RoPE + scatter
// Q,K -> [B,H,L,HD]; V -> transposed [B,H,HD,L] via LDS transpose.
// Q additionally scaled by HD^-0.5 * log2(e)  (exp2-domain softmax downstream).
// qkv rows have stride `rowstride` (combined QKV buffer support).
__global__ __launch_bounds__(256) void rope_scatter2(
    const bf16* __restrict__ qkv, int rowstride, const float* __restrict__ pos,
    bf16* __restrict__ Qo, bf16* __restrict__ Ko, bf16* __restrict__ Vtg)
{
    __shared__ float Vsh[64][65];   // conflict-free transpose staging
    int tid = threadIdx.x;
    int bid = blockIdx.x;
    int lt = bid & (NT - 1);
    int h  = (bid >> 5) & (H - 1);
    int b  = bid >> 9;
    int l0 = lt * 64;

    const float QSCALE = 0.18033688011111772f;  // 0.125 * log2(e)
    int hd = tid & 63, lq = tid >> 6;
    float sgn = (hd < 32) ? -1.f : 1.f;
    float invf = exp2f(-(float)(hd & 31) * (13.287712379549449f / 32.f));

    #pragma unroll
    for (int rr = 0; rr < 16; ++rr) {
        int l = l0 + lq * 16 + rr;
        size_t row = (size_t)(b * L + l) * rowstride;
        int col  = h * HD + hd;
        int col2 = h * HD + (hd ^ 32);

        float xq  = __bfloat162float(qkv[row + col]);
        float xq2 = __bfloat162float(qkv[row + col2]);
        float xk  = __bfloat162float(qkv[row + D + col]);
        float xk2 = __bfloat162float(qkv[row + D + col2]);
        float xv  = __bfloat162float(qkv[row + 2 * D + col]);

        float p = pos[b * L + l];
        float ang = p * invf;
        float cc = cosf(ang), ss = sinf(ang);

        float qo = QSCALE * (xq * cc + sgn * xq2 * ss);
        float ko = xk * cc + sgn * xk2 * ss;

        size_t o = ((size_t)(b * H + h) * L + l) * HD + hd;
        Qo[o] = __float2bfloat16(qo);
        Ko[o] = __float2bfloat16(ko);
        Vsh[l - l0][hd] = xv;
    }
    __syncthreads();
    int lcol = tid & 63, dq = tid >> 6;
    #pragma unroll
    for (int rr = 0; rr < 16; ++rr) {
        int dd = dq * 16 + rr;
        Vtg[((size_t)(b * H + h) * HD + dd) * L + l0 + lcol] = __float2bfloat16(Vsh[lcol][dd]);
    }
}

// ---------------------------------------------------------------- MFMA flash attention v6
// = v5 + QBLK=128: each wave owns 32 q rows (two 16-row groups g=0,1), so the same
//   K/V LDS tile reads feed 2x the MFMAs -> LDS-pipe pressure (the v5 bottleneck) halves.
// Grid: B*H*(L/128) = 512 blocks (%8==0, XCD swizzle kept).
// All v5-verified pieces unchanged: sigma-permuted K staging, operand-swapped QK^T,
// in-register P assembly, double-buffered LDS, one barrier/tile, post-barrier prefetch.
// branch 0 (intra): allowed = key_valid && cid_q==cid_k, writes float OutF.
// branch 1 (inter): allowed = key_valid && cid_q!=cid_k, writes bf16 OutB = o + Prev.
__global__ __launch_bounds__(256, 2) void attn6(
    const bf16* __restrict__ Q, const bf16* __restrict__ Kg, const bf16* __restrict__ Vtg,
    const int* __restrict__ cid, const int4* __restrict__ tinfo,
    float* __restrict__ OutF, bf16* __restrict__ OutB, const float* __restrict__ Prev,
    int branch)
{
    __shared__ short Ks[2][64][72];
    __shared__ short Vs[2][64][72];   // V^T tile: [dim][key]
    __shared__ int cls_s[NT];
    __shared__ int list_s[NT];
    __shared__ int nlist_s;

    int tid = threadIdx.x;
    int wave = tid >> 6, lane = tid & 63;
    int i15 = lane & 15, q8 = lane >> 4;
    // XCD swizzle: 512 blocks -> each XCD gets 64 contiguous work ids
    int workid = ((blockIdx.x & 7) << 6) | (blockIdx.x >> 3);
    int qt = workid & (NQT - 1);
    int h  = (workid >> 4) & (H - 1);
    int b  = workid >> 8;
    int q0 = qt * 128;
    const size_t bh  = (size_t)(b * H + h) * L;
    const size_t bhd = (size_t)(b * H + h) * HD;

    // Q fragments (B-operand of S^T), two 16-row groups per wave
    short8 qf[2][2];
    int cq[2];
    #pragma unroll
    for (int g = 0; g < 2; ++g) {
        const short* qp = (const short*)Q + (bh + q0 + g * 64 + wave * 16 + i15) * HD + q8 * 8;
        qf[g][0] = *(const short8*)(qp);
        qf[g][1] = *(const short8*)(qp + 32);
        cq[g] = cid[b * L + q0 + g * 64 + wave * 16 + i15];
    }

    // merge the two 64-q tinfo entries for this 128-q block
    int4 qa = tinfo[b * NT + 2 * qt];
    int4 qb4 = tinfo[b * NT + 2 * qt + 1];
    int4 qinf;
    qinf.x = min(qa.x, qb4.x);
    qinf.y = max(qa.y, qb4.y);
    qinf.z = ((qa.z | qb4.z) & 1) | (qa.z & qb4.z & 2);
    int qall = (qinf.z >> 1) & 1;

    if (tid < NT) {
        int4 ki = tinfo[b * NT + tid];
        int kany = ki.z & 1, kall = (ki.z >> 1) & 1;
        bool disjoint = (ki.x > qinf.y) || (ki.y < qinf.x);  // sentinels make !qany/!kany disjoint
        bool mono = qall && kall && (qinf.x == qinf.y) && (ki.x == ki.y) && (qinf.x == ki.x);
        int cls;
        if (branch == 0) {
            if (!kany || disjoint) cls = 0;
            else if (mono) cls = 2;
            else cls = 1;
        } else {
            if (!kany || mono) cls = 0;
            else if (kall && disjoint) cls = 2;
            else cls = 1;
        }
        cls_s[tid] = cls;
    }
    __syncthreads();
    if (tid == 0) {
        int n = 0;
        for (int t = 0; t < NT; ++t) {
            int c = cls_s[t];
            if (c) list_s[n++] = (t * 64) | ((c == 2) << 16);
        }
        nlist_s = n;
    }
    __syncthreads();
    int n = nlist_s;

    // staging geometry: thread -> row r, 16-short chunk ccol.
    // K stored at LDS row sigma(r) = 16*t(r)+m(r), t(r)=((r>>2)&1)|((r>>5)<<1),
    // m(r)=4*((r>>3)&3)+(r&3); reading row t*16+m yields K row (m&3)+4*(t&1)+8*(m>>2)+32*(t>>1).
    // V stored at plain row r (V^T: [dim][key]).
    int r = tid >> 2, ccol = (tid & 3) * 16;
    int sr = ((((r >> 2) & 1) | ((r >> 5) << 1)) << 4) | (((r >> 3) & 3) << 2) | (r & 3);
    const short* Kbase = (const short*)Kg  + (bh + r) * HD + ccol;
    const short* Vbase = (const short*)Vtg + (bhd + r) * L + ccol;

    int4 pk0, pk1, pv0, pv1;
    int cur = 0;
    if (n > 0) {
        cur = list_s[0];
        int kt0 = cur & 0xffff;
        pk0 = *(const int4*)(Kbase + (size_t)kt0 * HD);
        pk1 = *(const int4*)(Kbase + (size_t)kt0 * HD + 8);
        pv0 = *(const int4*)(Vbase + kt0);
        pv1 = *(const int4*)(Vbase + kt0 + 8);
    }

    floatx4 accO[2][4];
    #pragma unroll
    for (int g = 0; g < 2; ++g)
        #pragma unroll
        for (int t = 0; t < 4; ++t) accO[g][t] = (floatx4){0.f, 0.f, 0.f, 0.f};
    float lsum[2] = {0.f, 0.f};

    for (int i = 0; i < n; ++i) {
        int kt = cur & 0xffff, full = cur >> 16;
        int buf = i & 1;

        // stage tile i (prefetched regs already landed)
        *(int4*)&Ks[buf][sr][ccol]     = pk0;
        *(int4*)&Ks[buf][sr][ccol + 8] = pk1;
        *(int4*)&Vs[buf][r][ccol]      = pv0;
        *(int4*)&Vs[buf][r][ccol + 8]  = pv1;
        __syncthreads();

        // post-barrier: issue next tile's prefetch (covered by this tile's compute)
        if (i + 1 < n) {
            cur = list_s[i + 1];
            int nk = cur & 0xffff;
            pk0 = *(const int4*)(Kbase + (size_t)nk * HD);
            pk1 = *(const int4*)(Kbase + (size_t)nk * HD + 8);
            pv0 = *(const int4*)(Vbase + nk);
            pv1 = *(const int4*)(Vbase + nk + 8);
        }

        // S^T = K Q^T (log2 domain); lane's tile-t rows are k = 8*q8 + 4*(t&1) + 32*(t>>1) + rg
        unsigned int dl[2][4], dh[2][4];
        #pragma unroll
        for (int t = 0; t < 4; ++t) {
            short8 b0 = *(const short8*)&Ks[buf][t * 16 + i15][q8 * 8];
            short8 b1 = *(const short8*)&Ks[buf][t * 16 + i15][32 + q8 * 8];

            floatx4 accS[2];
            #pragma unroll
            for (int g = 0; g < 2; ++g) {
                accS[g] = (floatx4){0.f, 0.f, 0.f, 0.f};
                accS[g] = __builtin_amdgcn_mfma_f32_16x16x32_bf16(b0, qf[g][0], accS[g], 0, 0, 0);
                accS[g] = __builtin_amdgcn_mfma_f32_16x16x32_bf16(b1, qf[g][1], accS[g], 0, 0, 0);
            }

            if (!full) {
                int4 ck4 = *(const int4*)(cid + b * L + kt + (q8 << 3) + ((t & 1) << 2) + ((t >> 1) << 5));
                int ckr[4] = {ck4.x, ck4.y, ck4.z, ck4.w};
                #pragma unroll
                for (int g = 0; g < 2; ++g)
                    #pragma unroll
                    for (int rg = 0; rg < 4; ++rg) {
                        bool kv = (ckr[rg] != INVALID_CID);
                        bool match = (cq[g] == ckr[rg]);
                        bool ok = kv && (branch ? !match : match);
                        accS[g][rg] = ok ? accS[g][rg] : -1e30f;
                    }
            }

            #pragma unroll
            for (int g = 0; g < 2; ++g) {
                float p0 = __builtin_amdgcn_exp2f(accS[g][0]);
                float p1 = __builtin_amdgcn_exp2f(accS[g][1]);
                float p2 = __builtin_amdgcn_exp2f(accS[g][2]);
                float p3 = __builtin_amdgcn_exp2f(accS[g][3]);
                lsum[g] += (p0 + p1) + (p2 + p3);
                dl[g][t] = (unsigned int)(unsigned short)f2bf(p0) | ((unsigned int)(unsigned short)f2bf(p1) << 16);
                dh[g][t] = (unsigned int)(unsigned short)f2bf(p2) | ((unsigned int)(unsigned short)f2bf(p3) << 16);
            }
        }

        // P A-fragments in-register: pa0 -> k = 8*q8 + 0..7, pa1 -> k = 32 + 8*q8 + 0..7
        union { uint4v u; short8 s; } pa0[2], pa1[2];
        #pragma unroll
        for (int g = 0; g < 2; ++g) {
            pa0[g].u = (uint4v){dl[g][0], dh[g][0], dl[g][1], dh[g][1]};
            pa1[g].u = (uint4v){dl[g][2], dh[g][2], dl[g][3], dh[g][3]};
        }

        // O += P V  (B = V^T frags from LDS, shared across both q-groups)
        #pragma unroll
        for (int dt = 0; dt < 4; ++dt) {
            short8 vf0 = *(const short8*)&Vs[buf][dt * 16 + i15][q8 * 8];
            short8 vf1 = *(const short8*)&Vs[buf][dt * 16 + i15][32 + q8 * 8];
            #pragma unroll
            for (int g = 0; g < 2; ++g) {
                accO[g][dt] = __builtin_amdgcn_mfma_f32_16x16x32_bf16(pa0[g].s, vf0, accO[g][dt], 0, 0, 0);
                accO[g][dt] = __builtin_amdgcn_mfma_f32_16x16x32_bf16(pa1[g].s, vf1, accO[g][dt], 0, 0, 0);
            }
        }
    }

    // row-sum reduce + output, per q-group
    #pragma unroll
    for (int g = 0; g < 2; ++g) {
        float ls = lsum[g];
        ls += __shfl_xor(ls, 16, 64);
        ls += __shfl_xor(ls, 32, 64);
        float inv[4];
        #pragma unroll
        for (int rg = 0; rg < 4; ++rg) {
            float lv = __shfl(ls, q8 * 4 + rg, 64);   // lanes 0..15 hold q-locals 0..15
            inv[rg] = (lv > 0.f) ? 1.f / lv : 0.f;
        }
        #pragma unroll
        for (int t = 0; t < 4; ++t) {
            #pragma unroll
            for (int rg = 0; rg < 4; ++rg) {
                size_t idx = (size_t)(b * L + q0 + g * 64 + wave * 16 + q8 * 4 + rg) * D + h * HD + t * 16 + i15;
                float o = accO[g][t][rg] * inv[rg];
                if (branch == 0) OutF[idx] = o;
                else             OutB[idx] = __float2bfloat16(o + Prev[idx]);
            }
        }
    }
}

// ---------------------------------------------------------------- launch
extern "C" void kernel_launch(void* const* d_in, const int* in_sizes, int n_in,
                              void* d_out, int out_size, void* d_ws, size_t ws_size,
                              hipStream_t stream)
{
    const float* x    = (const float*)d_in[0];
    const int*   mlen = (const int*)  d_in[1];
    const float* Wi   = (const float*)d_in[2];
    const float* bi   = (const float*)d_in[3];
    const float* We   = (const float*)d_in[4];
    const float* be   = (const float*)d_in[5];
    const float* Wo   = (const float*)d_in[6];
    const float* bo   = (const float*)d_in[7];

    char* ws = (char*)d_ws;
    size_t off = 0;
    auto alloc = [&](size_t bytes) {
        void* p = ws + off;
        off += (bytes + 255) & ~(size_t)255;
        return p;
    };
    bf16*  x_b   = (bf16*) alloc((size_t)B * L * D * 2);
    bf16*  Wi_b  = (bf16*) alloc((size_t)3 * D * D * 2);   // adjacent to We_b: combined [6144][1024]
    bf16*  We_b  = (bf16*) alloc((size_t)3 * D * D * 2);
    bf16*  Wo_b  = (bf16*) alloc((size_t)D * D * 2);
    bf16*  qkv_b = (bf16*) alloc((size_t)B * L * 6 * D * 2);   // combined [B*L][6144]
    bf16*  q_b   = (bf16*) alloc((size_t)B * H * L * HD * 2);
    bf16*  k_b   = (bf16*) alloc((size_t)B * H * L * HD * 2);
    bf16*  vt_b  = (bf16*) alloc((size_t)B * H * HD * L * 2);
    float* att_i = (float*)alloc((size_t)B * L * D * 4);
    bf16*  sum_b = (bf16*) alloc((size_t)B * L * D * 2);
    float* pos   = (float*)alloc((size_t)B * L * 4);
    int*   cid   = (int*)  alloc((size_t)B * L * 4);
    int4*  tinfo = (int4*) alloc((size_t)B * NT * 16);
    (void)ws_size; (void)n_in; (void)in_sizes; (void)out_size;

    chain_kernel<<<B, 256, 0, stream>>>(mlen, pos, cid, tinfo);

    // fused bf16 casts: x(4096 blk) | Wi(3072) | We(3072) | Wo(1024)
    cast_all<<<11264, 256, 0, stream>>>(x, Wi, We, Wo, x_b, Wi_b, We_b, Wo_b);

    // one combined QKV GEMM: [4096,1024] x [6144,1024]^T -> [4096,6144]
    dim3 gq(6 * D / 128, B * L / 128);
    gemm128<<<gq, 256, 0, stream>>>(x_b, Wi_b, bi, be, qkv_b, B * L, 6 * D, D, 1, 3 * D);

    rope_scatter2<<<B * H * NT, 256, 0, stream>>>(qkv_b,         6 * D, pos, q_b, k_b, vt_b);
    attn6<<<B * H * NQT, 256, 0, stream>>>(q_b, k_b, vt_b, cid, tinfo, att_i, sum_b, att_i, 0);

    rope_scatter2<<<B * H * NT, 256, 0, stream>>>(qkv_b + 3 * D, 6 * D, pos, q_b, k_b, vt_b);
    attn6<<<B * H * NQT, 256, 0, stream>>>(q_b, k_b, vt_b, cid, tinfo, att_i, sum_b, att_i, 1);

    dim3 go(D / 128, B * L / 128);
    gemm128<<<go, 256, 0, stream>>>(sum_b, Wo_b, bo, bo, d_out, B * L, D, D, 0, D);
}

// Round 5
// 306.875 us; speedup vs baseline: 1.7315x; 1.0812x over previous
//
#include <hip/hip_runtime.h>
#include <hip/hip_bf16.h>
#include <stdint.h>

#define B 2
#define L 2048
#define D 1024
#define H 16
#define HD 64
#define NT (L / 64)          // 32 k-tiles of 64
#define NQT (L / 128)        // 16 q-tiles of 128
#define INVALID_CID 0x40000000
#define BHLHD ((size_t)B * H * L * HD)

typedef __hip_bfloat16 bf16;
typedef __attribute__((ext_vector_type(8))) short short8;
typedef __attribute__((ext_vector_type(4))) float floatx4;
typedef __attribute__((ext_vector_type(4))) unsigned int uint4v;

static __device__ __forceinline__ short f2bf(float f) {
    bf16 h = __float2bfloat16(f);
    return *reinterpret_cast<short*>(&h);
}

// async global->LDS, 16B per lane; lptr must be wave-uniform (HW adds lane*16)
static __device__ __forceinline__ void async_copy16(const void* g, void* l) {
    __builtin_amdgcn_global_load_lds((__attribute__((address_space(1))) void*)g,
                                     (__attribute__((address_space(3))) void*)l,
                                     16, 0, 0);
}

// ---------------------------------------------------------------- chain info
__global__ void chain_kernel(const int* __restrict__ lens,
                             float* __restrict__ pos, int* __restrict__ cid,
                             int4* __restrict__ tinfo)
{
    __shared__ int csum[L];
    __shared__ int cids[L];
    __shared__ int part[256];
    int b = blockIdx.x;
    int t = threadIdx.x;

    int loc[8];
    int s = 0;
    #pragma unroll
    for (int j = 0; j < 8; ++j) { s += lens[b * L + t * 8 + j]; loc[j] = s; }
    part[t] = s;
    __syncthreads();
    if (t == 0) {
        int acc = 0;
        for (int i = 0; i < 256; ++i) { int v = part[i]; part[i] = acc; acc += v; }
    }
    __syncthreads();
    int base = part[t];
    #pragma unroll
    for (int j = 0; j < 8; ++j) csum[t * 8 + j] = base + loc[j];
    __syncthreads();

    int total = csum[L - 1];
    for (int p = t; p < L; p += 256) {
        int cv;
        if (p < total) {
            int lo = 0, hi = L;
            while (lo < hi) {
                int mid = (lo + hi) >> 1;
                if (csum[mid] <= p) lo = mid + 1; else hi = mid;
            }
            int prev = (lo > 0) ? csum[lo - 1] : 0;
            pos[b * L + p] = (float)(p - prev);
            cv = lo;
        } else {
            pos[b * L + p] = 0.f;
            cv = INVALID_CID;
        }
        cids[p] = cv;
        cid[b * L + p] = cv;
    }
    __syncthreads();
    if (t < NT) {
        int mn = 0x7fffffff, mx = -1, any = 0, all = 1;
        for (int j = 0; j < 64; ++j) {
            int cv = cids[t * 64 + j];
            if (cv != INVALID_CID) { any = 1; mn = min(mn, cv); mx = max(mx, cv); }
            else all = 0;
        }
        tinfo[b * NT + t] = make_int4(mn, mx, any | (all << 1), 0);
    }
}

// ---------------------------------------------------------------- rope cos/sin table
// tab[bl][j] = (cos, sin)(pos[bl] * ropebase^(-j/32)), j = 0..31.  1 MB, L2-resident.
__global__ void rope_table(const float* __restrict__ pos, float2* __restrict__ tab)
{
    int idx = blockIdx.x * 256 + threadIdx.x;   // over B*L*32
    int j = idx & 31, l = idx >> 5;
    float invf = exp2f(-(float)j * (13.287712379549449f / 32.f));
    float ang = pos[l] * invf;
    tab[idx] = make_float2(cosf(ang), sinf(ang));
}

// ---------------------------------------------------------------- fused casts
// segments (1024 floats per block): x:4096 | Wi:3072 | We:3072 | Wo:1024  (all exact)
__global__ void cast_all(const float* __restrict__ x,  const float* __restrict__ Wi,
                         const float* __restrict__ We, const float* __restrict__ Wo,
                         bf16* __restrict__ xb, bf16* __restrict__ Wib,
                         bf16* __restrict__ Web, bf16* __restrict__ Wob)
{
    int bid = blockIdx.x;
    const float* src; bf16* dst; int base;
    if      (bid < 4096)  { src = x;  dst = xb;  base = bid; }
    else if (bid < 7168)  { src = Wi; dst = Wib; base = bid - 4096; }
    else if (bid < 10240) { src = We; dst = Web; base = bid - 7168; }
    else                  { src = Wo; dst = Wob; base = bid - 10240; }
    int i = (base * 256 + threadIdx.x) * 4;
    float4 v = *(const float4*)(src + i);
    dst[i + 0] = __float2bfloat16(v.x);
    dst[i + 1] = __float2bfloat16(v.y);
    dst[i + 2] = __float2bfloat16(v.z);
    dst[i + 3] = __float2bfloat16(v.w);
}

// ---------------------------------------------------------------- QKV GEMM + RoPE + scatter (fused)
// A:[4096,1024] bf16, Bw:[6144,1024] bf16 (Wi rows 0..3071, We rows 3072..6143).
// Wave owns 64 n-cols = exactly one (segment, head): seg = n>>10 in {Qi,Ki,Vi,Qe,Ke,Ve}.
// Epilogue applies bias (+RoPE for Q/K, Q also * HD^-0.5*log2e) in f32 and scatters:
//   Q,K -> [2][B,H,L,HD] bf16 ; V -> [2][B,H,HD,L] via per-wave LDS transpose.
// RoPE pair (hd, hd^32) = acc[mt][nt^2][rg] (same thread). cos/sin from tab.
__global__ __launch_bounds__(256, 4) void gemm_qkv(
    const bf16* __restrict__ A, const bf16* __restrict__ Bw,
    const float* __restrict__ bi, const float* __restrict__ be,
    const float2* __restrict__ tab,
    bf16* __restrict__ Qo, bf16* __restrict__ Ko, bf16* __restrict__ Vto)
{
    __shared__ short Smem[2 * 128 * 32];
    short* As = Smem;
    short* Bs = Smem + 128 * 32;

    int tid = threadIdx.x;
    int wave = tid >> 6, lane = tid & 63;
    int i15 = lane & 15, q8 = lane >> 4;
    int wm = wave & 1, wn = wave >> 1;
    int m0 = blockIdx.y * 128, n0 = blockIdx.x * 128;
    const int K = D;

    floatx4 acc[4][4];
    #pragma unroll
    for (int mt = 0; mt < 4; ++mt)
        #pragma unroll
        for (int nt = 0; nt < 4; ++nt) acc[mt][nt] = (floatx4){0.f, 0.f, 0.f, 0.f};

    const short* gA = (const short*)A  + (size_t)(m0 + wave * 32 + (lane >> 2)) * K + (lane & 3) * 8;
    const short* gB = (const short*)Bw + (size_t)(n0 + wave * 32 + (lane >> 2)) * K + (lane & 3) * 8;
    short* lA = As + wave * 1024;
    short* lB = Bs + wave * 1024;

    for (int kt = 0; kt < K; kt += 32) {
        __syncthreads();
        async_copy16(gA + kt,          lA);
        async_copy16(gA + 16 * K + kt, lA + 512);
        async_copy16(gB + kt,          lB);
        async_copy16(gB + 16 * K + kt, lB + 512);
        __syncthreads();

        short8 af[4], bfr[4];
        #pragma unroll
        for (int mt = 0; mt < 4; ++mt)
            af[mt] = *(const short8*)&As[(wm * 64 + mt * 16 + i15) * 32 + q8 * 8];
        #pragma unroll
        for (int nt = 0; nt < 4; ++nt)
            bfr[nt] = *(const short8*)&Bs[(wn * 64 + nt * 16 + i15) * 32 + q8 * 8];
        #pragma unroll
        for (int mt = 0; mt < 4; ++mt)
            #pragma unroll
            for (int nt = 0; nt < 4; ++nt)
                acc[mt][nt] = __builtin_amdgcn_mfma_f32_16x16x32_bf16(af[mt], bfr[nt], acc[mt][nt], 0, 0, 0);
    }

    // ---- epilogue ----
    int nb = n0 + wn * 64;               // wave's first col; 64 cols = one (seg, head)
    int segw = nb >> 10;                 // 0 Qi, 1 Ki, 2 Vi, 3 Qe, 4 Ke, 5 Ve
    int br = (segw >= 3);
    int st = segw - 3 * br;              // 0 Q, 1 K, 2 V
    int h = (nb >> 6) & (H - 1);
    int b = m0 >> 11;                    // m0 / L
    int lb = (m0 & (L - 1)) + wm * 64;   // wave's first l

    float bv[4];
    #pragma unroll
    for (int nt = 0; nt < 4; ++nt) {
        int n = nb + nt * 16 + i15;
        bv[nt] = (n < 3 * D) ? bi[n] : be[n - 3 * D];
    }

    if (st != 2) {
        // Q or K: bias + RoPE, write [B,H,L,HD]
        bf16* out = (st == 0 ? Qo : Ko) + (size_t)br * BHLHD;
        const size_t bh = (size_t)(b * H + h) * L;
        float qs = (st == 0) ? 0.18033688011111772f : 1.0f;   // 0.125 * log2(e)
        #pragma unroll
        for (int mt = 0; mt < 4; ++mt) {
            #pragma unroll
            for (int rg = 0; rg < 4; ++rg) {
                int m = m0 + wm * 64 + mt * 16 + q8 * 4 + rg;     // global row
                int l = lb + mt * 16 + q8 * 4 + rg;
                float2 cs0 = tab[(size_t)m * 32 + i15];
                float2 cs1 = tab[(size_t)m * 32 + 16 + i15];
                size_t orow = (bh + l) * HD;
                #pragma unroll
                for (int nt = 0; nt < 4; ++nt) {
                    float x  = acc[mt][nt][rg] + bv[nt];
                    float pr = acc[mt][nt ^ 2][rg] + bv[nt ^ 2];
                    float cc = (nt & 1) ? cs1.x : cs0.x;
                    float ss = (nt & 1) ? cs1.y : cs0.y;
                    float v = qs * (x * cc + ((nt < 2) ? -pr : pr) * ss);
                    out[orow + nt * 16 + i15] = __float2bfloat16(v);
                }
            }
        }
    } else {
        // V: bias, per-wave LDS transpose (reuse staging LDS), write [B,H,HD,L]
        bf16* out = Vto + (size_t)br * BHLHD;
        const size_t bhd = (size_t)(b * H + h) * HD;
        __syncthreads();                      // all waves done reading As/Bs
        short* vts = Smem + wave * 64 * 20;   // [64 hd][20] shorts, rows 40 B (bank-safe, 8B-aligned)
        #pragma unroll
        for (int mt = 0; mt < 4; ++mt) {
            #pragma unroll
            for (int nt = 0; nt < 4; ++nt) {
                uint2 w;
                w.x = (unsigned)(unsigned short)f2bf(acc[mt][nt][0] + bv[nt]) |
                      ((unsigned)(unsigned short)f2bf(acc[mt][nt][1] + bv[nt]) << 16);
                w.y = (unsigned)(unsigned short)f2bf(acc[mt][nt][2] + bv[nt]) |
                      ((unsigned)(unsigned short)f2bf(acc[mt][nt][3] + bv[nt]) << 16);
                *(uint2*)&vts[(nt * 16 + i15) * 20 + q8 * 4] = w;   // row hd, cols m-local
            }
            // same-wave read back: lane <-> hd row, 16 m-local shorts
            uint2 r0 = *(const uint2*)&vts[lane * 20 + 0];
            uint2 r1 = *(const uint2*)&vts[lane * 20 + 4];
            uint2 r2 = *(const uint2*)&vts[lane * 20 + 8];
            uint2 r3 = *(const uint2*)&vts[lane * 20 + 12];
            size_t ga = (bhd + lane) * L + lb + mt * 16;
            uint4v v0 = (uint4v){r0.x, r0.y, r1.x, r1.y};
            uint4v v1 = (uint4v){r2.x, r2.y, r3.x, r3.y};
            *(uint4v*)&out[ga]     = v0;
            *(uint4v*)&out[ga + 8] = v1;
        }
    }
}

// ---------------------------------------------------------------- GEMM (m97-style, out-proj)
// C = A * Bw^T + bias.  A:[M,K] bf16 rm, Bw:[N,K] bf16 rm. 128x128 tile, BK=32.
__global__ __launch_bounds__(256, 4) void gemm128(
    const bf16* __restrict__ A, const bf16* __restrict__ Bw,
    const float* __restrict__ bias, void* __restrict__ Cout,
    int M, int N, int K, int c_bf16)
{
    __shared__ short As[128 * 32];
    __shared__ short Bs[128 * 32];

    int tid = threadIdx.x;
    int wave = tid >> 6, lane = tid & 63;
    int i15 = lane & 15, q8 = lane >> 4;
    int wm = wave & 1, wn = wave >> 1;
    int m0 = blockIdx.y * 128, n0 = blockIdx.x * 128;

    floatx4 acc[4][4];
    #pragma unroll
    for (int mt = 0; mt < 4; ++mt)
        #pragma unroll
        for (int nt = 0; nt < 4; ++nt) acc[mt][nt] = (floatx4){0.f, 0.f, 0.f, 0.f};

    const short* gA = (const short*)A  + (size_t)(m0 + wave * 32 + (lane >> 2)) * K + (lane & 3) * 8;
    const short* gB = (const short*)Bw + (size_t)(n0 + wave * 32 + (lane >> 2)) * K + (lane & 3) * 8;
    short* lA = As + wave * 1024;
    short* lB = Bs + wave * 1024;

    for (int kt = 0; kt < K; kt += 32) {
        __syncthreads();
        async_copy16(gA + kt,          lA);
        async_copy16(gA + 16 * K + kt, lA + 512);
        async_copy16(gB + kt,          lB);
        async_copy16(gB + 16 * K + kt, lB + 512);
        __syncthreads();

        short8 af[4], bfr[4];
        #pragma unroll
        for (int mt = 0; mt < 4; ++mt)
            af[mt] = *(const short8*)&As[(wm * 64 + mt * 16 + i15) * 32 + q8 * 8];
        #pragma unroll
        for (int nt = 0; nt < 4; ++nt)
            bfr[nt] = *(const short8*)&Bs[(wn * 64 + nt * 16 + i15) * 32 + q8 * 8];
        #pragma unroll
        for (int mt = 0; mt < 4; ++mt)
            #pragma unroll
            for (int nt = 0; nt < 4; ++nt)
                acc[mt][nt] = __builtin_amdgcn_mfma_f32_16x16x32_bf16(af[mt], bfr[nt], acc[mt][nt], 0, 0, 0);
    }

    #pragma unroll
    for (int nt = 0; nt < 4; ++nt) {
        int n = n0 + wn * 64 + nt * 16 + i15;
        float bv = bias[n];
        #pragma unroll
        for (int mt = 0; mt < 4; ++mt) {
            #pragma unroll
            for (int rg = 0; rg < 4; ++rg) {
                int m = m0 + wm * 64 + mt * 16 + q8 * 4 + rg;
                float v = acc[mt][nt][rg] + bv;
                if (c_bf16) ((bf16*)Cout)[(size_t)m * N + n] = __float2bfloat16(v);
                else        ((float*)Cout)[(size_t)m * N + n] = v;
            }
        }
    }
}

// ---------------------------------------------------------------- MFMA flash attention v6
// (unchanged from round 4; QBLK=128, sigma-permuted K staging, operand-swapped QK^T,
//  in-register P, double-buffered LDS, one barrier/tile, XCD swizzle.)
__global__ __launch_bounds__(256, 2) void attn6(
    const bf16* __restrict__ Q, const bf16* __restrict__ Kg, const bf16* __restrict__ Vtg,
    const int* __restrict__ cid, const int4* __restrict__ tinfo,
    float* __restrict__ OutF, bf16* __restrict__ OutB, const float* __restrict__ Prev,
    int branch)
{
    __shared__ short Ks[2][64][72];
    __shared__ short Vs[2][64][72];
    __shared__ int cls_s[NT];
    __shared__ int list_s[NT];
    __shared__ int nlist_s;

    int tid = threadIdx.x;
    int wave = tid >> 6, lane = tid & 63;
    int i15 = lane & 15, q8 = lane >> 4;
    int workid = ((blockIdx.x & 7) << 6) | (blockIdx.x >> 3);
    int qt = workid & (NQT - 1);
    int h  = (workid >> 4) & (H - 1);
    int b  = workid >> 8;
    int q0 = qt * 128;
    const size_t bh  = (size_t)(b * H + h) * L;
    const size_t bhd = (size_t)(b * H + h) * HD;

    short8 qf[2][2];
    int cq[2];
    #pragma unroll
    for (int g = 0; g < 2; ++g) {
        const short* qp = (const short*)Q + (bh + q0 + g * 64 + wave * 16 + i15) * HD + q8 * 8;
        qf[g][0] = *(const short8*)(qp);
        qf[g][1] = *(const short8*)(qp + 32);
        cq[g] = cid[b * L + q0 + g * 64 + wave * 16 + i15];
    }

    int4 qa = tinfo[b * NT + 2 * qt];
    int4 qb4 = tinfo[b * NT + 2 * qt + 1];
    int4 qinf;
    qinf.x = min(qa.x, qb4.x);
    qinf.y = max(qa.y, qb4.y);
    qinf.z = ((qa.z | qb4.z) & 1) | (qa.z & qb4.z & 2);
    int qall = (qinf.z >> 1) & 1;

    if (tid < NT) {
        int4 ki = tinfo[b * NT + tid];
        int kany = ki.z & 1, kall = (ki.z >> 1) & 1;
        bool disjoint = (ki.x > qinf.y) || (ki.y < qinf.x);
        bool mono = qall && kall && (qinf.x == qinf.y) && (ki.x == ki.y) && (qinf.x == ki.x);
        int cls;
        if (branch == 0) {
            if (!kany || disjoint) cls = 0;
            else if (mono) cls = 2;
            else cls = 1;
        } else {
            if (!kany || mono) cls = 0;
            else if (kall && disjoint) cls = 2;
            else cls = 1;
        }
        cls_s[tid] = cls;
    }
    __syncthreads();
    if (tid == 0) {
        int n = 0;
        for (int t = 0; t < NT; ++t) {
            int c = cls_s[t];
            if (c) list_s[n++] = (t * 64) | ((c == 2) << 16);
        }
        nlist_s = n;
    }
    __syncthreads();
    int n = nlist_s;

    int r = tid >> 2, ccol = (tid & 3) * 16;
    int sr = ((((r >> 2) & 1) | ((r >> 5) << 1)) << 4) | (((r >> 3) & 3) << 2) | (r & 3);
    const short* Kbase = (const short*)Kg  + (bh + r) * HD + ccol;
    const short* Vbase = (const short*)Vtg + (bhd + r) * L + ccol;

    int4 pk0, pk1, pv0, pv1;
    int cur = 0;
    if (n > 0) {
        cur = list_s[0];
        int kt0 = cur & 0xffff;
        pk0 = *(const int4*)(Kbase + (size_t)kt0 * HD);
        pk1 = *(const int4*)(Kbase + (size_t)kt0 * HD + 8);
        pv0 = *(const int4*)(Vbase + kt0);
        pv1 = *(const int4*)(Vbase + kt0 + 8);
    }

    floatx4 accO[2][4];
    #pragma unroll
    for (int g = 0; g < 2; ++g)
        #pragma unroll
        for (int t = 0; t < 4; ++t) accO[g][t] = (floatx4){0.f, 0.f, 0.f, 0.f};
    float lsum[2] = {0.f, 0.f};

    for (int i = 0; i < n; ++i) {
        int kt = cur & 0xffff, full = cur >> 16;
        int buf = i & 1;

        *(int4*)&Ks[buf][sr][ccol]     = pk0;
        *(int4*)&Ks[buf][sr][ccol + 8] = pk1;
        *(int4*)&Vs[buf][r][ccol]      = pv0;
        *(int4*)&Vs[buf][r][ccol + 8]  = pv1;
        __syncthreads();

        if (i + 1 < n) {
            cur = list_s[i + 1];
            int nk = cur & 0xffff;
            pk0 = *(const int4*)(Kbase + (size_t)nk * HD);
            pk1 = *(const int4*)(Kbase + (size_t)nk * HD + 8);
            pv0 = *(const int4*)(Vbase + nk);
            pv1 = *(const int4*)(Vbase + nk + 8);
        }

        unsigned int dl[2][4], dh[2][4];
        #pragma unroll
        for (int t = 0; t < 4; ++t) {
            short8 b0 = *(const short8*)&Ks[buf][t * 16 + i15][q8 * 8];
            short8 b1 = *(const short8*)&Ks[buf][t * 16 + i15][32 + q8 * 8];

            floatx4 accS[2];
            #pragma unroll
            for (int g = 0; g < 2; ++g) {
                accS[g] = (floatx4){0.f, 0.f, 0.f, 0.f};
                accS[g] = __builtin_amdgcn_mfma_f32_16x16x32_bf16(b0, qf[g][0], accS[g], 0, 0, 0);
                accS[g] = __builtin_amdgcn_mfma_f32_16x16x32_bf16(b1, qf[g][1], accS[g], 0, 0, 0);
            }

            if (!full) {
                int4 ck4 = *(const int4*)(cid + b * L + kt + (q8 << 3) + ((t & 1) << 2) + ((t >> 1) << 5));
                int ckr[4] = {ck4.x, ck4.y, ck4.z, ck4.w};
                #pragma unroll
                for (int g = 0; g < 2; ++g)
                    #pragma unroll
                    for (int rg = 0; rg < 4; ++rg) {
                        bool kv = (ckr[rg] != INVALID_CID);
                        bool match = (cq[g] == ckr[rg]);
                        bool ok = kv && (branch ? !match : match);
                        accS[g][rg] = ok ? accS[g][rg] : -1e30f;
                    }
            }

            #pragma unroll
            for (int g = 0; g < 2; ++g) {
                float p0 = __builtin_amdgcn_exp2f(accS[g][0]);
                float p1 = __builtin_amdgcn_exp2f(accS[g][1]);
                float p2 = __builtin_amdgcn_exp2f(accS[g][2]);
                float p3 = __builtin_amdgcn_exp2f(accS[g][3]);
                lsum[g] += (p0 + p1) + (p2 + p3);
                dl[g][t] = (unsigned int)(unsigned short)f2bf(p0) | ((unsigned int)(unsigned short)f2bf(p1) << 16);
                dh[g][t] = (unsigned int)(unsigned short)f2bf(p2) | ((unsigned int)(unsigned short)f2bf(p3) << 16);
            }
        }

        union { uint4v u; short8 s; } pa0[2], pa1[2];
        #pragma unroll
        for (int g = 0; g < 2; ++g) {
            pa0[g].u = (uint4v){dl[g][0], dh[g][0], dl[g][1], dh[g][1]};
            pa1[g].u = (uint4v){dl[g][2], dh[g][2], dl[g][3], dh[g][3]};
        }

        #pragma unroll
        for (int dt = 0; dt < 4; ++dt) {
            short8 vf0 = *(const short8*)&Vs[buf][dt * 16 + i15][q8 * 8];
            short8 vf1 = *(const short8*)&Vs[buf][dt * 16 + i15][32 + q8 * 8];
            #pragma unroll
            for (int g = 0; g < 2; ++g) {
                accO[g][dt] = __builtin_amdgcn_mfma_f32_16x16x32_bf16(pa0[g].s, vf0, accO[g][dt], 0, 0, 0);
                accO[g][dt] = __builtin_amdgcn_mfma_f32_16x16x32_bf16(pa1[g].s, vf1, accO[g][dt], 0, 0, 0);
            }
        }
    }

    #pragma unroll
    for (int g = 0; g < 2; ++g) {
        float ls = lsum[g];
        ls += __shfl_xor(ls, 16, 64);
        ls += __shfl_xor(ls, 32, 64);
        float inv[4];
        #pragma unroll
        for (int rg = 0; rg < 4; ++rg) {
            float lv = __shfl(ls, q8 * 4 + rg, 64);
            inv[rg] = (lv > 0.f) ? 1.f / lv : 0.f;
        }
        #pragma unroll
        for (int t = 0; t < 4; ++t) {
            #pragma unroll
            for (int rg = 0; rg < 4; ++rg) {
                size_t idx = (size_t)(b * L + q0 + g * 64 + wave * 16 + q8 * 4 + rg) * D + h * HD + t * 16 + i15;
                float o = accO[g][t][rg] * inv[rg];
                if (branch == 0) OutF[idx] = o;
                else             OutB[idx] = __float2bfloat16(o + Prev[idx]);
            }
        }
    }
}

// ---------------------------------------------------------------- launch
extern "C" void kernel_launch(void* const* d_in, const int* in_sizes, int n_in,
                              void* d_out, int out_size, void* d_ws, size_t ws_size,
                              hipStream_t stream)
{
    const float* x    = (const float*)d_in[0];
    const int*   mlen = (const int*)  d_in[1];
    const float* Wi   = (const float*)d_in[2];
    const float* bi   = (const float*)d_in[3];
    const float* We   = (const float*)d_in[4];
    const float* be   = (const float*)d_in[5];
    const float* Wo   = (const float*)d_in[6];
    const float* bo   = (const float*)d_in[7];

    char* ws = (char*)d_ws;
    size_t off = 0;
    auto alloc = [&](size_t bytes) {
        void* p = ws + off;
        off += (bytes + 255) & ~(size_t)255;
        return p;
    };
    bf16*  x_b   = (bf16*) alloc((size_t)B * L * D * 2);
    bf16*  Wi_b  = (bf16*) alloc((size_t)3 * D * D * 2);   // adjacent to We_b: combined [6144][1024]
    bf16*  We_b  = (bf16*) alloc((size_t)3 * D * D * 2);
    bf16*  Wo_b  = (bf16*) alloc((size_t)D * D * 2);
    bf16*  q_b   = (bf16*) alloc(2 * BHLHD * 2);           // [branch][B,H,L,HD]
    bf16*  k_b   = (bf16*) alloc(2 * BHLHD * 2);
    bf16*  vt_b  = (bf16*) alloc(2 * BHLHD * 2);           // [branch][B,H,HD,L]
    float* att_i = (float*)alloc((size_t)B * L * D * 4);
    bf16*  sum_b = (bf16*) alloc((size_t)B * L * D * 2);
    float* pos   = (float*)alloc((size_t)B * L * 4);
    int*   cid   = (int*)  alloc((size_t)B * L * 4);
    int4*  tinfo = (int4*) alloc((size_t)B * NT * 16);
    float2* rtab = (float2*)alloc((size_t)B * L * 32 * 8);
    (void)ws_size; (void)n_in; (void)in_sizes; (void)out_size;

    chain_kernel<<<B, 256, 0, stream>>>(mlen, pos, cid, tinfo);
    rope_table<<<B * L * 32 / 256, 256, 0, stream>>>(pos, rtab);

    // fused bf16 casts: x(4096 blk) | Wi(3072) | We(3072) | Wo(1024)
    cast_all<<<11264, 256, 0, stream>>>(x, Wi, We, Wo, x_b, Wi_b, We_b, Wo_b);

    // fused QKV GEMM + bias + RoPE + scatter (both branches in one pass)
    dim3 gq(6 * D / 128, B * L / 128);
    gemm_qkv<<<gq, 256, 0, stream>>>(x_b, Wi_b, bi, be, rtab, q_b, k_b, vt_b);

    attn6<<<B * H * NQT, 256, 0, stream>>>(q_b, k_b, vt_b, cid, tinfo, att_i, sum_b, att_i, 0);
    attn6<<<B * H * NQT, 256, 0, stream>>>(q_b + BHLHD, k_b + BHLHD, vt_b + BHLHD,
                                           cid, tinfo, att_i, sum_b, att_i, 1);

    dim3 go(D / 128, B * L / 128);
    gemm128<<<go, 256, 0, stream>>>(sum_b, Wo_b, bo, d_out, B * L, D, D, 0);
}

// Round 6
// 290.141 us; speedup vs baseline: 1.8313x; 1.0577x over previous
//
#include <hip/hip_runtime.h>
#include <hip/hip_bf16.h>
#include <stdint.h>

#define B 2
#define L 2048
#define D 1024
#define H 16
#define HD 64
#define NT (L / 64)          // 32 k-tiles of 64
#define NQT (L / 128)        // 16 q-tiles of 128
#define INVALID_CID 0x40000000
#define BHLHD ((size_t)B * H * L * HD)

typedef __hip_bfloat16 bf16;
typedef __attribute__((ext_vector_type(8))) short short8;
typedef __attribute__((ext_vector_type(4))) float floatx4;
typedef __attribute__((ext_vector_type(4))) unsigned int uint4v;

static __device__ __forceinline__ short f2bf(float f) {
    bf16 h = __float2bfloat16(f);
    return *reinterpret_cast<short*>(&h);
}

// async global->LDS, 16B per lane; lptr must be wave-uniform (HW adds lane*16)
static __device__ __forceinline__ void async_copy16(const void* g, void* l) {
    __builtin_amdgcn_global_load_lds((__attribute__((address_space(1))) void*)g,
                                     (__attribute__((address_space(3))) void*)l,
                                     16, 0, 0);
}

// ---------------------------------------------------------------- chain info
__global__ void chain_kernel(const int* __restrict__ lens,
                             float* __restrict__ pos, int* __restrict__ cid,
                             int4* __restrict__ tinfo)
{
    __shared__ int csum[L];
    __shared__ int cids[L];
    __shared__ int part[256];
    int b = blockIdx.x;
    int t = threadIdx.x;

    int loc[8];
    int s = 0;
    #pragma unroll
    for (int j = 0; j < 8; ++j) { s += lens[b * L + t * 8 + j]; loc[j] = s; }
    part[t] = s;
    __syncthreads();
    if (t == 0) {
        int acc = 0;
        for (int i = 0; i < 256; ++i) { int v = part[i]; part[i] = acc; acc += v; }
    }
    __syncthreads();
    int base = part[t];
    #pragma unroll
    for (int j = 0; j < 8; ++j) csum[t * 8 + j] = base + loc[j];
    __syncthreads();

    int total = csum[L - 1];
    for (int p = t; p < L; p += 256) {
        int cv;
        if (p < total) {
            int lo = 0, hi = L;
            while (lo < hi) {
                int mid = (lo + hi) >> 1;
                if (csum[mid] <= p) lo = mid + 1; else hi = mid;
            }
            int prev = (lo > 0) ? csum[lo - 1] : 0;
            pos[b * L + p] = (float)(p - prev);
            cv = lo;
        } else {
            pos[b * L + p] = 0.f;
            cv = INVALID_CID;
        }
        cids[p] = cv;
        cid[b * L + p] = cv;
    }
    __syncthreads();
    if (t < NT) {
        int mn = 0x7fffffff, mx = -1, any = 0, all = 1;
        for (int j = 0; j < 64; ++j) {
            int cv = cids[t * 64 + j];
            if (cv != INVALID_CID) { any = 1; mn = min(mn, cv); mx = max(mx, cv); }
            else all = 0;
        }
        tinfo[b * NT + t] = make_int4(mn, mx, any | (all << 1), 0);
    }
}

// ---------------------------------------------------------------- rope cos/sin table
// tab[bl][j] = (cos, sin)(pos[bl] * ropebase^(-j/32)), j = 0..31.  1 MB, L2-resident.
__global__ void rope_table(const float* __restrict__ pos, float2* __restrict__ tab)
{
    int idx = blockIdx.x * 256 + threadIdx.x;   // over B*L*32
    int j = idx & 31, l = idx >> 5;
    float invf = exp2f(-(float)j * (13.287712379549449f / 32.f));
    float ang = pos[l] * invf;
    tab[idx] = make_float2(cosf(ang), sinf(ang));
}

// ---------------------------------------------------------------- fused casts
// segments (1024 floats per block): x:4096 | Wi:3072 | We:3072 | Wo:1024  (all exact)
__global__ void cast_all(const float* __restrict__ x,  const float* __restrict__ Wi,
                         const float* __restrict__ We, const float* __restrict__ Wo,
                         bf16* __restrict__ xb, bf16* __restrict__ Wib,
                         bf16* __restrict__ Web, bf16* __restrict__ Wob)
{
    int bid = blockIdx.x;
    const float* src; bf16* dst; int base;
    if      (bid < 4096)  { src = x;  dst = xb;  base = bid; }
    else if (bid < 7168)  { src = Wi; dst = Wib; base = bid - 4096; }
    else if (bid < 10240) { src = We; dst = Web; base = bid - 7168; }
    else                  { src = Wo; dst = Wob; base = bid - 10240; }
    int i = (base * 256 + threadIdx.x) * 4;
    float4 v = *(const float4*)(src + i);
    dst[i + 0] = __float2bfloat16(v.x);
    dst[i + 1] = __float2bfloat16(v.y);
    dst[i + 2] = __float2bfloat16(v.z);
    dst[i + 3] = __float2bfloat16(v.w);
}

// ---------------------------------------------------------------- QKV GEMM + RoPE + scatter (fused)
// A:[4096,1024] bf16, Bw:[6144,1024] bf16 (Wi rows 0..3071, We rows 3072..6143).
// Wave owns 64 n-cols = exactly one (segment, head): seg = n>>10 in {Qi,Ki,Vi,Qe,Ke,Ve}.
// Epilogue applies bias (+RoPE for Q/K, Q also * HD^-0.5*log2e) in f32 and scatters:
//   Q,K -> [2][B,H,L,HD] bf16 ; V -> [2][B,H,HD,L] via per-wave LDS transpose.
// RoPE pair (hd, hd^32) = acc[mt][nt^2][rg] (same thread). cos/sin from tab.
__global__ __launch_bounds__(256, 4) void gemm_qkv(
    const bf16* __restrict__ A, const bf16* __restrict__ Bw,
    const float* __restrict__ bi, const float* __restrict__ be,
    const float2* __restrict__ tab,
    bf16* __restrict__ Qo, bf16* __restrict__ Ko, bf16* __restrict__ Vto)
{
    __shared__ short Smem[2 * 128 * 32];
    short* As = Smem;
    short* Bs = Smem + 128 * 32;

    int tid = threadIdx.x;
    int wave = tid >> 6, lane = tid & 63;
    int i15 = lane & 15, q8 = lane >> 4;
    int wm = wave & 1, wn = wave >> 1;
    int m0 = blockIdx.y * 128, n0 = blockIdx.x * 128;
    const int K = D;

    floatx4 acc[4][4];
    #pragma unroll
    for (int mt = 0; mt < 4; ++mt)
        #pragma unroll
        for (int nt = 0; nt < 4; ++nt) acc[mt][nt] = (floatx4){0.f, 0.f, 0.f, 0.f};

    const short* gA = (const short*)A  + (size_t)(m0 + wave * 32 + (lane >> 2)) * K + (lane & 3) * 8;
    const short* gB = (const short*)Bw + (size_t)(n0 + wave * 32 + (lane >> 2)) * K + (lane & 3) * 8;
    short* lA = As + wave * 1024;
    short* lB = Bs + wave * 1024;

    for (int kt = 0; kt < K; kt += 32) {
        __syncthreads();
        async_copy16(gA + kt,          lA);
        async_copy16(gA + 16 * K + kt, lA + 512);
        async_copy16(gB + kt,          lB);
        async_copy16(gB + 16 * K + kt, lB + 512);
        __syncthreads();

        short8 af[4], bfr[4];
        #pragma unroll
        for (int mt = 0; mt < 4; ++mt)
            af[mt] = *(const short8*)&As[(wm * 64 + mt * 16 + i15) * 32 + q8 * 8];
        #pragma unroll
        for (int nt = 0; nt < 4; ++nt)
            bfr[nt] = *(const short8*)&Bs[(wn * 64 + nt * 16 + i15) * 32 + q8 * 8];
        #pragma unroll
        for (int mt = 0; mt < 4; ++mt)
            #pragma unroll
            for (int nt = 0; nt < 4; ++nt)
                acc[mt][nt] = __builtin_amdgcn_mfma_f32_16x16x32_bf16(af[mt], bfr[nt], acc[mt][nt], 0, 0, 0);
    }

    // ---- epilogue ----
    int nb = n0 + wn * 64;               // wave's first col; 64 cols = one (seg, head)
    int segw = nb >> 10;                 // 0 Qi, 1 Ki, 2 Vi, 3 Qe, 4 Ke, 5 Ve
    int br = (segw >= 3);
    int st = segw - 3 * br;              // 0 Q, 1 K, 2 V
    int h = (nb >> 6) & (H - 1);
    int b = m0 >> 11;                    // m0 / L
    int lb = (m0 & (L - 1)) + wm * 64;   // wave's first l

    float bv[4];
    #pragma unroll
    for (int nt = 0; nt < 4; ++nt) {
        int n = nb + nt * 16 + i15;
        bv[nt] = (n < 3 * D) ? bi[n] : be[n - 3 * D];
    }

    if (st != 2) {
        // Q or K: bias + RoPE, write [B,H,L,HD]
        bf16* out = (st == 0 ? Qo : Ko) + (size_t)br * BHLHD;
        const size_t bh = (size_t)(b * H + h) * L;
        float qs = (st == 0) ? 0.18033688011111772f : 1.0f;   // 0.125 * log2(e)
        #pragma unroll
        for (int mt = 0; mt < 4; ++mt) {
            #pragma unroll
            for (int rg = 0; rg < 4; ++rg) {
                int m = m0 + wm * 64 + mt * 16 + q8 * 4 + rg;     // global row
                int l = lb + mt * 16 + q8 * 4 + rg;
                float2 cs0 = tab[(size_t)m * 32 + i15];
                float2 cs1 = tab[(size_t)m * 32 + 16 + i15];
                size_t orow = (bh + l) * HD;
                #pragma unroll
                for (int nt = 0; nt < 4; ++nt) {
                    float x  = acc[mt][nt][rg] + bv[nt];
                    float pr = acc[mt][nt ^ 2][rg] + bv[nt ^ 2];
                    float cc = (nt & 1) ? cs1.x : cs0.x;
                    float ss = (nt & 1) ? cs1.y : cs0.y;
                    float v = qs * (x * cc + ((nt < 2) ? -pr : pr) * ss);
                    out[orow + nt * 16 + i15] = __float2bfloat16(v);
                }
            }
        }
    } else {
        // V: bias, per-wave LDS transpose (reuse staging LDS), write [B,H,HD,L]
        bf16* out = Vto + (size_t)br * BHLHD;
        const size_t bhd = (size_t)(b * H + h) * HD;
        __syncthreads();                      // all waves done reading As/Bs (uniform per block)
        short* vts = Smem + wave * 64 * 20;   // [64 hd][20] shorts, rows 40 B (bank-safe, 8B-aligned)
        #pragma unroll
        for (int mt = 0; mt < 4; ++mt) {
            #pragma unroll
            for (int nt = 0; nt < 4; ++nt) {
                uint2 w;
                w.x = (unsigned)(unsigned short)f2bf(acc[mt][nt][0] + bv[nt]) |
                      ((unsigned)(unsigned short)f2bf(acc[mt][nt][1] + bv[nt]) << 16);
                w.y = (unsigned)(unsigned short)f2bf(acc[mt][nt][2] + bv[nt]) |
                      ((unsigned)(unsigned short)f2bf(acc[mt][nt][3] + bv[nt]) << 16);
                *(uint2*)&vts[(nt * 16 + i15) * 20 + q8 * 4] = w;   // row hd, cols m-local
            }
            // same-wave read back: lane <-> hd row, 16 m-local shorts
            uint2 r0 = *(const uint2*)&vts[lane * 20 + 0];
            uint2 r1 = *(const uint2*)&vts[lane * 20 + 4];
            uint2 r2 = *(const uint2*)&vts[lane * 20 + 8];
            uint2 r3 = *(const uint2*)&vts[lane * 20 + 12];
            size_t ga = (bhd + lane) * L + lb + mt * 16;
            uint4v v0 = (uint4v){r0.x, r0.y, r1.x, r1.y};
            uint4v v1 = (uint4v){r2.x, r2.y, r3.x, r3.y};
            *(uint4v*)&out[ga]     = v0;
            *(uint4v*)&out[ga + 8] = v1;
        }
    }
}

// ---------------------------------------------------------------- GEMM (m97-style, out-proj)
__global__ __launch_bounds__(256, 4) void gemm128(
    const bf16* __restrict__ A, const bf16* __restrict__ Bw,
    const float* __restrict__ bias, void* __restrict__ Cout,
    int M, int N, int K, int c_bf16)
{
    __shared__ short As[128 * 32];
    __shared__ short Bs[128 * 32];

    int tid = threadIdx.x;
    int wave = tid >> 6, lane = tid & 63;
    int i15 = lane & 15, q8 = lane >> 4;
    int wm = wave & 1, wn = wave >> 1;
    int m0 = blockIdx.y * 128, n0 = blockIdx.x * 128;

    floatx4 acc[4][4];
    #pragma unroll
    for (int mt = 0; mt < 4; ++mt)
        #pragma unroll
        for (int nt = 0; nt < 4; ++nt) acc[mt][nt] = (floatx4){0.f, 0.f, 0.f, 0.f};

    const short* gA = (const short*)A  + (size_t)(m0 + wave * 32 + (lane >> 2)) * K + (lane & 3) * 8;
    const short* gB = (const short*)Bw + (size_t)(n0 + wave * 32 + (lane >> 2)) * K + (lane & 3) * 8;
    short* lA = As + wave * 1024;
    short* lB = Bs + wave * 1024;

    for (int kt = 0; kt < K; kt += 32) {
        __syncthreads();
        async_copy16(gA + kt,          lA);
        async_copy16(gA + 16 * K + kt, lA + 512);
        async_copy16(gB + kt,          lB);
        async_copy16(gB + 16 * K + kt, lB + 512);
        __syncthreads();

        short8 af[4], bfr[4];
        #pragma unroll
        for (int mt = 0; mt < 4; ++mt)
            af[mt] = *(const short8*)&As[(wm * 64 + mt * 16 + i15) * 32 + q8 * 8];
        #pragma unroll
        for (int nt = 0; nt < 4; ++nt)
            bfr[nt] = *(const short8*)&Bs[(wn * 64 + nt * 16 + i15) * 32 + q8 * 8];
        #pragma unroll
        for (int mt = 0; mt < 4; ++mt)
            #pragma unroll
            for (int nt = 0; nt < 4; ++nt)
                acc[mt][nt] = __builtin_amdgcn_mfma_f32_16x16x32_bf16(af[mt], bfr[nt], acc[mt][nt], 0, 0, 0);
    }

    #pragma unroll
    for (int nt = 0; nt < 4; ++nt) {
        int n = n0 + wn * 64 + nt * 16 + i15;
        float bv = bias[n];
        #pragma unroll
        for (int mt = 0; mt < 4; ++mt) {
            #pragma unroll
            for (int rg = 0; rg < 4; ++rg) {
                int m = m0 + wm * 64 + mt * 16 + q8 * 4 + rg;
                float v = acc[mt][nt][rg] + bv;
                if (c_bf16) ((bf16*)Cout)[(size_t)m * N + n] = __float2bfloat16(v);
                else        ((float*)Cout)[(size_t)m * N + n] = v;
            }
        }
    }
}

// ---------------------------------------------------------------- MFMA flash attention v7
// BOTH branches in ONE dispatch: per block, phase br=0 (intra) then br=1 (inter) over the
// same 128-q tile; final write is bf16(o_i*inv_i + o_e*inv_e) directly -> the 16.8 MB f32
// intermediate round-trip and the duplicate prologue/list-build are gone.
// Inner loop identical to v6 (verified): sigma-permuted K staging, operand-swapped QK^T,
// in-register P, double-buffered LDS, one barrier/tile, post-barrier prefetch, XCD swizzle.
__global__ __launch_bounds__(256, 2) void attn7(
    const bf16* __restrict__ Qg, const bf16* __restrict__ Kgg, const bf16* __restrict__ Vtgg,
    const int* __restrict__ cid, const int4* __restrict__ tinfo,
    bf16* __restrict__ Out)
{
    __shared__ short Ks[2][64][72];
    __shared__ short Vs[2][64][72];   // V^T tile: [dim][key]
    __shared__ int cls0_s[NT], cls1_s[NT];
    __shared__ int list_s[2][NT];
    __shared__ int nlist_s[2];

    int tid = threadIdx.x;
    int wave = tid >> 6, lane = tid & 63;
    int i15 = lane & 15, q8 = lane >> 4;
    int workid = ((blockIdx.x & 7) << 6) | (blockIdx.x >> 3);   // 512 blocks, XCD-chunked
    int qt = workid & (NQT - 1);
    int h  = (workid >> 4) & (H - 1);
    int b  = workid >> 8;
    int q0 = qt * 128;
    const size_t bh  = (size_t)(b * H + h) * L;
    const size_t bhd = (size_t)(b * H + h) * HD;

    int cq[2];
    #pragma unroll
    for (int g = 0; g < 2; ++g)
        cq[g] = cid[b * L + q0 + g * 64 + wave * 16 + i15];

    // merge the two 64-q tinfo entries for this 128-q block
    int4 qa = tinfo[b * NT + 2 * qt];
    int4 qb4 = tinfo[b * NT + 2 * qt + 1];
    int4 qinf;
    qinf.x = min(qa.x, qb4.x);
    qinf.y = max(qa.y, qb4.y);
    qinf.z = ((qa.z | qb4.z) & 1) | (qa.z & qb4.z & 2);
    int qall = (qinf.z >> 1) & 1;

    if (tid < NT) {
        int4 ki = tinfo[b * NT + tid];
        int kany = ki.z & 1, kall = (ki.z >> 1) & 1;
        bool disjoint = (ki.x > qinf.y) || (ki.y < qinf.x);
        bool mono = qall && kall && (qinf.x == qinf.y) && (ki.x == ki.y) && (qinf.x == ki.x);
        cls0_s[tid] = (!kany || disjoint) ? 0 : (mono ? 2 : 1);
        cls1_s[tid] = (!kany || mono) ? 0 : ((kall && disjoint) ? 2 : 1);
    }
    __syncthreads();
    if (tid < 2) {
        const int* cls = tid ? cls1_s : cls0_s;
        int n = 0;
        for (int t = 0; t < NT; ++t) {
            int c = cls[t];
            if (c) list_s[tid][n++] = (t * 64) | ((c == 2) << 16);
        }
        nlist_s[tid] = n;
    }
    __syncthreads();

    // staging geometry (thread -> row r, 16-short chunk ccol); sigma-permuted K rows
    int r = tid >> 2, ccol = (tid & 3) * 16;
    int sr = ((((r >> 2) & 1) | ((r >> 5) << 1)) << 4) | (((r >> 3) & 3) << 2) | (r & 3);

    floatx4 accO[2][2][4];   // [branch][g][t]
    #pragma unroll
    for (int br = 0; br < 2; ++br)
        #pragma unroll
        for (int g = 0; g < 2; ++g)
            #pragma unroll
            for (int t = 0; t < 4; ++t) accO[br][g][t] = (floatx4){0.f, 0.f, 0.f, 0.f};
    float lsum[2][2] = {{0.f, 0.f}, {0.f, 0.f}};

    #pragma unroll
    for (int br = 0; br < 2; ++br) {
        const short* Qb    = (const short*)Qg  + (size_t)br * BHLHD;
        const short* Kbase = (const short*)Kgg + (size_t)br * BHLHD + (bh + r) * HD + ccol;
        const short* Vbase = (const short*)Vtgg + (size_t)br * BHLHD + (bhd + r) * L + ccol;
        int n = nlist_s[br];

        // Q fragments for this branch
        short8 qf[2][2];
        #pragma unroll
        for (int g = 0; g < 2; ++g) {
            const short* qp = Qb + (bh + q0 + g * 64 + wave * 16 + i15) * HD + q8 * 8;
            qf[g][0] = *(const short8*)(qp);
            qf[g][1] = *(const short8*)(qp + 32);
        }

        int4 pk0, pk1, pv0, pv1;
        int cur = 0;
        if (n > 0) {
            cur = list_s[br][0];
            int kt0 = cur & 0xffff;
            pk0 = *(const int4*)(Kbase + (size_t)kt0 * HD);
            pk1 = *(const int4*)(Kbase + (size_t)kt0 * HD + 8);
            pv0 = *(const int4*)(Vbase + kt0);
            pv1 = *(const int4*)(Vbase + kt0 + 8);
        }
        __syncthreads();   // prior phase's reads done before overwriting buffers

        for (int i = 0; i < n; ++i) {
            int kt = cur & 0xffff, full = cur >> 16;
            int buf = i & 1;

            *(int4*)&Ks[buf][sr][ccol]     = pk0;
            *(int4*)&Ks[buf][sr][ccol + 8] = pk1;
            *(int4*)&Vs[buf][r][ccol]      = pv0;
            *(int4*)&Vs[buf][r][ccol + 8]  = pv1;
            __syncthreads();

            if (i + 1 < n) {
                cur = list_s[br][i + 1];
                int nk = cur & 0xffff;
                pk0 = *(const int4*)(Kbase + (size_t)nk * HD);
                pk1 = *(const int4*)(Kbase + (size_t)nk * HD + 8);
                pv0 = *(const int4*)(Vbase + nk);
                pv1 = *(const int4*)(Vbase + nk + 8);
            }

            // S^T = K Q^T (log2 domain); lane's tile-t rows: k = 8*q8 + 4*(t&1) + 32*(t>>1) + rg
            unsigned int dl[2][4], dh[2][4];
            #pragma unroll
            for (int t = 0; t < 4; ++t) {
                short8 b0 = *(const short8*)&Ks[buf][t * 16 + i15][q8 * 8];
                short8 b1 = *(const short8*)&Ks[buf][t * 16 + i15][32 + q8 * 8];

                floatx4 accS[2];
                #pragma unroll
                for (int g = 0; g < 2; ++g) {
                    accS[g] = (floatx4){0.f, 0.f, 0.f, 0.f};
                    accS[g] = __builtin_amdgcn_mfma_f32_16x16x32_bf16(b0, qf[g][0], accS[g], 0, 0, 0);
                    accS[g] = __builtin_amdgcn_mfma_f32_16x16x32_bf16(b1, qf[g][1], accS[g], 0, 0, 0);
                }

                if (!full) {
                    int4 ck4 = *(const int4*)(cid + b * L + kt + (q8 << 3) + ((t & 1) << 2) + ((t >> 1) << 5));
                    int ckr[4] = {ck4.x, ck4.y, ck4.z, ck4.w};
                    #pragma unroll
                    for (int g = 0; g < 2; ++g)
                        #pragma unroll
                        for (int rg = 0; rg < 4; ++rg) {
                            bool kv = (ckr[rg] != INVALID_CID);
                            bool match = (cq[g] == ckr[rg]);
                            bool ok = kv && (br ? !match : match);
                            accS[g][rg] = ok ? accS[g][rg] : -1e30f;
                        }
                }

                #pragma unroll
                for (int g = 0; g < 2; ++g) {
                    float p0 = __builtin_amdgcn_exp2f(accS[g][0]);
                    float p1 = __builtin_amdgcn_exp2f(accS[g][1]);
                    float p2 = __builtin_amdgcn_exp2f(accS[g][2]);
                    float p3 = __builtin_amdgcn_exp2f(accS[g][3]);
                    lsum[br][g] += (p0 + p1) + (p2 + p3);
                    dl[g][t] = (unsigned)(unsigned short)f2bf(p0) | ((unsigned)(unsigned short)f2bf(p1) << 16);
                    dh[g][t] = (unsigned)(unsigned short)f2bf(p2) | ((unsigned)(unsigned short)f2bf(p3) << 16);
                }
            }

            union { uint4v u; short8 s; } pa0[2], pa1[2];
            #pragma unroll
            for (int g = 0; g < 2; ++g) {
                pa0[g].u = (uint4v){dl[g][0], dh[g][0], dl[g][1], dh[g][1]};
                pa1[g].u = (uint4v){dl[g][2], dh[g][2], dl[g][3], dh[g][3]};
            }

            #pragma unroll
            for (int dt = 0; dt < 4; ++dt) {
                short8 vf0 = *(const short8*)&Vs[buf][dt * 16 + i15][q8 * 8];
                short8 vf1 = *(const short8*)&Vs[buf][dt * 16 + i15][32 + q8 * 8];
                #pragma unroll
                for (int g = 0; g < 2; ++g) {
                    accO[br][g][dt] = __builtin_amdgcn_mfma_f32_16x16x32_bf16(pa0[g].s, vf0, accO[br][g][dt], 0, 0, 0);
                    accO[br][g][dt] = __builtin_amdgcn_mfma_f32_16x16x32_bf16(pa1[g].s, vf1, accO[br][g][dt], 0, 0, 0);
                }
            }
        }
    }

    // row-sum reduce per branch/group, then single bf16 output write
    float inv[2][2][4];
    #pragma unroll
    for (int br = 0; br < 2; ++br)
        #pragma unroll
        for (int g = 0; g < 2; ++g) {
            float ls = lsum[br][g];
            ls += __shfl_xor(ls, 16, 64);
            ls += __shfl_xor(ls, 32, 64);
            #pragma unroll
            for (int rg = 0; rg < 4; ++rg) {
                float lv = __shfl(ls, q8 * 4 + rg, 64);
                inv[br][g][rg] = (lv > 0.f) ? 1.f / lv : 0.f;
            }
        }

    #pragma unroll
    for (int g = 0; g < 2; ++g)
        #pragma unroll
        for (int t = 0; t < 4; ++t)
            #pragma unroll
            for (int rg = 0; rg < 4; ++rg) {
                size_t idx = (size_t)(b * L + q0 + g * 64 + wave * 16 + q8 * 4 + rg) * D + h * HD + t * 16 + i15;
                float o = accO[0][g][t][rg] * inv[0][g][rg] + accO[1][g][t][rg] * inv[1][g][rg];
                Out[idx] = __float2bfloat16(o);
            }
}

// ---------------------------------------------------------------- launch
extern "C" void kernel_launch(void* const* d_in, const int* in_sizes, int n_in,
                              void* d_out, int out_size, void* d_ws, size_t ws_size,
                              hipStream_t stream)
{
    const float* x    = (const float*)d_in[0];
    const int*   mlen = (const int*)  d_in[1];
    const float* Wi   = (const float*)d_in[2];
    const float* bi   = (const float*)d_in[3];
    const float* We   = (const float*)d_in[4];
    const float* be   = (const float*)d_in[5];
    const float* Wo   = (const float*)d_in[6];
    const float* bo   = (const float*)d_in[7];

    char* ws = (char*)d_ws;
    size_t off = 0;
    auto alloc = [&](size_t bytes) {
        void* p = ws + off;
        off += (bytes + 255) & ~(size_t)255;
        return p;
    };
    bf16*  x_b   = (bf16*) alloc((size_t)B * L * D * 2);
    bf16*  Wi_b  = (bf16*) alloc((size_t)3 * D * D * 2);   // adjacent to We_b: combined [6144][1024]
    bf16*  We_b  = (bf16*) alloc((size_t)3 * D * D * 2);
    bf16*  Wo_b  = (bf16*) alloc((size_t)D * D * 2);
    bf16*  q_b   = (bf16*) alloc(2 * BHLHD * 2);           // [branch][B,H,L,HD]
    bf16*  k_b   = (bf16*) alloc(2 * BHLHD * 2);
    bf16*  vt_b  = (bf16*) alloc(2 * BHLHD * 2);           // [branch][B,H,HD,L]
    bf16*  sum_b = (bf16*) alloc((size_t)B * L * D * 2);
    float* pos   = (float*)alloc((size_t)B * L * 4);
    int*   cid   = (int*)  alloc((size_t)B * L * 4);
    int4*  tinfo = (int4*) alloc((size_t)B * NT * 16);
    float2* rtab = (float2*)alloc((size_t)B * L * 32 * 8);
    (void)ws_size; (void)n_in; (void)in_sizes; (void)out_size;

    chain_kernel<<<B, 256, 0, stream>>>(mlen, pos, cid, tinfo);
    rope_table<<<B * L * 32 / 256, 256, 0, stream>>>(pos, rtab);

    // fused bf16 casts: x(4096 blk) | Wi(3072) | We(3072) | Wo(1024)
    cast_all<<<11264, 256, 0, stream>>>(x, Wi, We, Wo, x_b, Wi_b, We_b, Wo_b);

    // fused QKV GEMM + bias + RoPE + scatter (both branches in one pass)
    dim3 gq(6 * D / 128, B * L / 128);
    gemm_qkv<<<gq, 256, 0, stream>>>(x_b, Wi_b, bi, be, rtab, q_b, k_b, vt_b);

    // both attention branches in one dispatch
    attn7<<<B * H * NQT, 256, 0, stream>>>(q_b, k_b, vt_b, cid, tinfo, sum_b);

    dim3 go(D / 128, B * L / 128);
    gemm128<<<go, 256, 0, stream>>>(sum_b, Wo_b, bo, d_out, B * L, D, D, 0);
}